// Round 9
// baseline (293.394 us; speedup 1.0000x reference)
//
#include <hip/hip_runtime.h>
#include <math.h>

// ---------------------------------------------------------------------------
// HimNet multimode v12r (resubmit; round-8 bench was an infra failure).
// B=8,N=1000,CIN=16,H=64,D=16,K=3,XIN=80,K*XIN=240,2H=128
//
// v12 = v11 (prep_v, merged aux, cheb unchanged) + meta3 rebuilt on the v8
// barrier-free geometry with the remat-killer:
//   - wave = 64 rows x 16 cols (mi=4, ni=1), unique B per wave, B loaded
//     global->VGPR from fragment-linear pack (1KB coalesced per wave-load,
//     L2-resident). No LDS/barriers in the d-loop.
//   - after the afr hoist: dynamic-index LDS write + kept-live read-back
//     over As => ds_read remat illegal => afr must stay in registers; with
//     no class constraint the allocator uses AGPRs (v6-proven mechanism;
//     v9's "+v" forced VGPR class and spilled).
// Evidence: gate(2.93 blk/CU) == update(1.46 blk/CU) == 52us -> per-block
// serial chain bound; FLOP floor ~4us, L2 floor ~11us.
// ---------------------------------------------------------------------------

typedef __attribute__((ext_vector_type(8))) short s16x8;
typedef __attribute__((ext_vector_type(4))) float f32x4;
typedef unsigned short u16;
typedef unsigned int u32;
typedef unsigned long long u64;

__device__ __forceinline__ u32 f2bf(float f) {
  union { float f; u32 u; } v; v.f = f;
  return (v.u + 0x7FFFu + ((v.u >> 16) & 1u)) >> 16;  // RNE
}
__device__ __forceinline__ float bf2f(u16 h) {
  union { u32 u; float f; } v; v.u = (u32)h << 16; return v.f;
}
__device__ __forceinline__ u64 pk4(float a, float b, float c, float d) {
  return (u64)f2bf(a) | ((u64)f2bf(b) << 16) | ((u64)f2bf(c) << 32) |
         ((u64)f2bf(d) << 48);
}
__device__ __forceinline__ void glds16(const u16* g, u16* l) {
  __builtin_amdgcn_global_load_lds(
      (const __attribute__((address_space(1))) void*)g,
      (__attribute__((address_space(3))) void*)l, 16, 0, 0);
}

// ---------------------------------------------------------------------------
// prep_v: vectorized 4 elems/thread (v11).
// ---------------------------------------------------------------------------
#define E0 3145728
#define E1 1966080
#define E2 1920000
#define E3 384000
#define E4 384000
#define E5 384000
#define E6 119808
// total = 8303616 elems = 2075904 threads = 8109 * 256

struct PrepArgs {
  const float* x[3]; const float* st[3]; const float* S[3];
  u16 *S16, *Xt, *Ag, *AgU, *T1t, *ZSt, *SZ1t;
};

__global__ void prep_v(PrepArgs P) {
  long idx = ((long)blockIdx.x * 256 + threadIdx.x) * 4;
  if (idx < E0) {  // S16 incl pads: 4 consecutive k, same n
    int m = (int)(idx >> 20); int rem = (int)(idx & 1048575);
    int n = rem >> 10, k = rem & 1023;
    u64 pv = 0;
    if (n < 1000 && k < 1000) {
      f32x4 v = *(const f32x4*)&P.S[m][n * 1000 + k];
      pv = pk4(v[0], v[1], v[2], v[3]);
    }
    *(u64*)&P.S16[(size_t)m * 1048576 + rem] = pv; return;
  }
  idx -= E0;
  if (idx < E1) {  // Xt: 4 consecutive nn, same col
    int m = (int)(idx / 655360); int rem = (int)(idx % 655360);
    int col = rem >> 10, nn = rem & 1023;
    int b = col / 80, c = col % 80;
    u64 pv = 0;
    if (nn < 1000) {
      float f[4];
#pragma unroll
      for (int j = 0; j < 4; ++j)
        f[j] = (c < 16) ? P.x[m][(b * 1000 + nn + j) * 16 + c]
                        : P.st[m][(b * 1000 + nn + j) * 64 + c - 16];
      pv = pk4(f[0], f[1], f[2], f[3]);
    }
    *(u64*)&P.Xt[(size_t)m * 655360 + rem] = pv; return;
  }
  idx -= E1;
  if (idx < E2) {  // Ag kc0: 4 consecutive c, same r
    int m = (int)(idx / 640000); int rem = (int)(idx % 640000);
    int r = rem / 80, c = rem % 80;
    int n = r >> 3, b = r & 7;
    f32x4 v = (c < 16) ? *(const f32x4*)&P.x[m][(b * 1000 + n) * 16 + c]
                       : *(const f32x4*)&P.st[m][(b * 1000 + n) * 64 + c - 16];
    *(u64*)&P.Ag[(size_t)m * 2048000 + (size_t)r * 256 + c] =
        pk4(v[0], v[1], v[2], v[3]);
    return;
  }
  idx -= E2;
  if (idx < E3) {  // Ag K-pad 240..255
    int m = (int)(idx / 128000); int rem = (int)(idx % 128000);
    int r = rem / 16, c = 240 + rem % 16;
    *(u64*)&P.Ag[(size_t)m * 2048000 + (size_t)r * 256 + c] = 0; return;
  }
  idx -= E3;
  if (idx < E4) {  // AgU kc0 x-part (cols 0..15)
    int m = (int)(idx / 128000); int rem = (int)(idx % 128000);
    int r = rem / 16, c = rem % 16;
    int n = r >> 3, b = r & 7;
    f32x4 v = *(const f32x4*)&P.x[m][(b * 1000 + n) * 16 + c];
    *(u64*)&P.AgU[(size_t)m * 2048000 + (size_t)r * 256 + c] =
        pk4(v[0], v[1], v[2], v[3]);
    return;
  }
  idx -= E4;
  if (idx < E5) {  // AgU K-pad
    int m = (int)(idx / 128000); int rem = (int)(idx % 128000);
    int r = rem / 16, c = 240 + rem % 16;
    *(u64*)&P.AgU[(size_t)m * 2048000 + (size_t)r * 256 + c] = 0; return;
  }
  idx -= E5;
  if (idx < E6) {  // n-pad rows (k=1000..1023) of T1t/ZSt/SZ1t
    int m = (int)(idx / 39936); int rem = (int)(idx % 39936);
    if (rem < 15360) { int col = rem / 24, j = rem % 24;
      *(u64*)&P.T1t[(size_t)m * 655360 + col * 1024 + 1000 + j] = 0; }
    else if (rem < 27648) { int e = rem - 15360; int col = e / 24, j = e % 24;
      *(u64*)&P.ZSt[(size_t)m * 524288 + col * 1024 + 1000 + j] = 0; }
    else { int e = rem - 27648; int col = e / 24, j = e % 24;
      *(u64*)&P.SZ1t[(size_t)m * 524288 + col * 1024 + 1000 + j] = 0; }
    return;
  }
}

// ---------------------------------------------------------------------------
// aux: BiG + BiU + packW(frag-linear gate) + packW(frag-linear update).
// Bt_f[((d*J + j)*8 + ki)*64 + lane][e] = W[d][k][o],
//   k = ki*32 + (lane>>4)*8 + e, o = j*16 + (lane&15), 0 pad.
// ---------------------------------------------------------------------------
__global__ void aux_kernel(const float* __restrict__ e0, const float* __restrict__ e1,
                           const float* __restrict__ e2, const float* __restrict__ me,
                           const float* __restrict__ Bg, const float* __restrict__ Bu,
                           const float* __restrict__ Wg, const float* __restrict__ Wu,
                           float* __restrict__ BiG, float* __restrict__ BiU,
                           u16* __restrict__ BtG, u16* __restrict__ BtU) {
  int idx = blockIdx.x * blockDim.x + threadIdx.x;
  if (idx < 384000) {        // BiG[mode][n*128+o]
    int mode = idx / 128000, rem = idx % 128000;
    int n = rem >> 7, o = rem & 127;
    const float* emb = (mode == 0) ? e0 : (mode == 1) ? e1 : e2;
    float s = 0.f;
#pragma unroll
    for (int d = 0; d < 16; ++d)
      s += emb[n * 16 + d] * me[mode * 16 + d] * Bg[d * 128 + o];
    BiG[idx] = s; return;
  }
  idx -= 384000;
  if (idx < 192000) {        // BiU[mode][n*64+o]
    int mode = idx / 64000, rem = idx % 64000;
    int n = rem >> 6, o = rem & 63;
    const float* emb = (mode == 0) ? e0 : (mode == 1) ? e1 : e2;
    float s = 0.f;
#pragma unroll
    for (int d = 0; d < 16; ++d)
      s += emb[n * 16 + d] * me[mode * 16 + d] * Bu[d * 64 + o];
    BiU[idx] = s; return;
  }
  idx -= 192000;
  if (idx < 524288) {        // BtG fragment-linear (J=8)
    int e = idx & 7, lane = (idx >> 3) & 63, ki = (idx >> 9) & 7;
    int j = (idx >> 12) & 7, d = idx >> 15;
    int k = ki * 32 + (lane >> 4) * 8 + e;
    int o = j * 16 + (lane & 15);
    BtG[idx] = (k < 240) ? (u16)f2bf(Wg[d * 30720 + k * 128 + o]) : (u16)0;
    return;
  }
  idx -= 524288;
  {                          // BtU fragment-linear (J=4)
    int e = idx & 7, lane = (idx >> 3) & 63, ki = (idx >> 9) & 7;
    int j = (idx >> 12) & 3, d = idx >> 14;
    int k = ki * 32 + (lane >> 4) * 8 + e;
    int o = j * 16 + (lane & 15);
    BtU[idx] = (k < 240) ? (u16)f2bf(Wu[d * 15360 + k * 64 + o]) : (u16)0;
  }
}

// ---------------------------------------------------------------------------
// cheb_v4: unchanged (v4 structure).
// ---------------------------------------------------------------------------
struct ChebArgs2 {
  const u16* S16[3]; const u16* A[3]; const u16* Res[3];
  u16* Yt[3]; u16* AgA[3]; u16* AgX[3];
};

__global__ __launch_bounds__(256, 2) void cheb_v4(ChebArgs2 g, int fdiv, int agbase,
                                                  float alpha, float beta, int flags) {
  const int mode = blockIdx.z;
  const u16* __restrict__ Ab = g.A[mode];
  const u16* __restrict__ Sb = g.S16[mode];

  __shared__ u16 As[64 * 64];
  __shared__ u16 Bs[64 * 64];

  const int t = threadIdx.x;
  const int row0 = blockIdx.y * 64, n0 = blockIdx.x * 64;
  const int lane = t & 63, wid = t >> 6;
  const int l16 = lane & 15, quad = lane >> 4;
  const int wy = (wid >> 1) * 32, wx = (wid & 1) * 32;

  f32x4 acc[2][2];
#pragma unroll
  for (int a = 0; a < 2; ++a)
#pragma unroll
    for (int b = 0; b < 2; ++b) acc[a][b] = (f32x4){0.f, 0.f, 0.f, 0.f};

  for (int k0 = 0; k0 < 1024; k0 += 64) {
#pragma unroll
    for (int p = 0; p < 2; ++p) {  // A: 64x64 = 512 chunks
      int idx = p * 256 + t; int row = idx >> 3; int cs = (idx & 7) ^ (row & 7);
      glds16(Ab + (size_t)(row0 + row) * 1024 + k0 + cs * 8, &As[idx * 8]);
    }
#pragma unroll
    for (int p = 0; p < 2; ++p) {  // B: 64x64 = 512 chunks
      int idx = p * 256 + t; int row = idx >> 3; int cs = (idx & 7) ^ (row & 7);
      glds16(Sb + (size_t)(n0 + row) * 1024 + k0 + cs * 8, &Bs[idx * 8]);
    }
    __syncthreads();
    s16x8 af[2][2], bf[2][2];
#pragma unroll
    for (int mi = 0; mi < 2; ++mi) {
      int row = wy + mi * 16 + l16;
#pragma unroll
      for (int ks = 0; ks < 2; ++ks) {
        int cl = (ks * 4 + quad) ^ (row & 7);
        af[mi][ks] = *(const s16x8*)&As[row * 64 + cl * 8];
      }
    }
#pragma unroll
    for (int ni = 0; ni < 2; ++ni) {
      int row = wx + ni * 16 + l16;
#pragma unroll
      for (int ks = 0; ks < 2; ++ks) {
        int cl = (ks * 4 + quad) ^ (row & 7);
        bf[ni][ks] = *(const s16x8*)&Bs[row * 64 + cl * 8];
      }
    }
#pragma unroll
    for (int ks = 0; ks < 2; ++ks)
#pragma unroll
      for (int mi = 0; mi < 2; ++mi)
#pragma unroll
        for (int ni = 0; ni < 2; ++ni)
          acc[mi][ni] = __builtin_amdgcn_mfma_f32_16x16x32_bf16(af[mi][ks], bf[ni][ks], acc[mi][ni], 0, 0, 0);
    __syncthreads();
  }

#pragma unroll
  for (int mi = 0; mi < 2; ++mi) {
    int frow0 = row0 + wy + mi * 16 + quad * 4;
    int b = frow0 / fdiv, c0 = frow0 - b * fdiv;
#pragma unroll
    for (int ni = 0; ni < 2; ++ni) {
      int n = n0 + wx + ni * 16 + l16;
      if (n < 1000) {
        u16 pk[4];
#pragma unroll
        for (int r = 0; r < 4; ++r) {
          float v = alpha * acc[mi][ni][r];
          if (flags & 1) v += beta * bf2f(g.Res[mode][(size_t)(frow0 + r) * 1024 + n]);
          u16 h = (u16)f2bf(v);
          pk[r] = h;
          if (flags & 2) g.Yt[mode][(size_t)(frow0 + r) * 1024 + n] = h;
        }
        u64 pv = (u64)pk[0] | ((u64)pk[1] << 16) | ((u64)pk[2] << 32) | ((u64)pk[3] << 48);
        *(u64*)&g.AgA[mode][(size_t)(n * 8 + b) * 256 + agbase + c0] = pv;
        if ((flags & 4) && c0 < 16)
          *(u64*)&g.AgX[mode][(size_t)(n * 8 + b) * 256 + agbase + c0] = pv;
      }
    }
  }
}

// ---------------------------------------------------------------------------
// meta3 v12: wave = 64 rows x 16 cols (jw = oc*4+wid). A staged through LDS
// once, hoisted to afr[4][8]; remat killed by a may-alias LDS write +
// kept-live read-back (no register-class constraints -> AGPR residency,
// v6 mechanism). d-loop: 8 coalesced 1KB B loads (unique per wave) +
// 32 MFMA + fold, barrier-free.
// ---------------------------------------------------------------------------
struct Meta3Args {
  const u16* Ag;        // [3][8000][256]
  const u16* Bt;        // fragment-linear pack
  const float* emb[3];
  const float* me;
  const float* Bias;    // [3][1000][O]
  const float* state[3];
  u16* ZSt;             // [3][512][1024]
  u16* AgU;             // [3][8000][256]
  float* Rb;            // [3][8000][64]
  float* out;
};

__global__ __launch_bounds__(256, 2) void meta3(Meta3Args A, int is_gate, int O) {
  const int mode = blockIdx.z;
  const int row0 = blockIdx.y * 64;
  const int n0 = row0 >> 3;
  const int oc = blockIdx.x;          // out-col block: gate 0/1, update 0
  const int J = O >> 4;               // 16-col groups per d (8 gate, 4 update)

  __shared__ u16 As[64 * 256];   // 32KB: A-prologue stage only
  __shared__ float ewS[8][17];

  const int t = threadIdx.x;
  if (t < 128) {
    int nl = t >> 4, d = t & 15;
    ewS[nl][d] = A.emb[mode][(n0 + nl) * 16 + d] * A.me[mode * 16 + d];
  }

  const int lane = t & 63, wid = t >> 6;
  const int l16 = lane & 15, quad = lane >> 4;
  const u16* Agm = A.Ag + (size_t)mode * 2048000;

  // prologue: stage A rows [row0,row0+64) x K256, hoist to registers
#pragma unroll
  for (int p = 0; p < 8; ++p) {
    int idx = p * 256 + t; int row = idx >> 5; int cs = (idx & 31) ^ (row & 7);
    glds16(Agm + (size_t)(row0 + row) * 256 + cs * 8, &As[idx * 8]);
  }
  __syncthreads();

  s16x8 afr[4][8];   // all 64 rows of A; AGPR-resident after remat-kill
#pragma unroll
  for (int mi = 0; mi < 4; ++mi) {
    int row = mi * 16 + l16;
#pragma unroll
    for (int ki = 0; ki < 8; ++ki) {
      int cl = (ki * 4 + quad) ^ (row & 7);
      afr[mi][ki] = *(const s16x8*)&As[row * 256 + cl * 8];
    }
  }
  __syncthreads();   // all hoist reads retired
  // remat-killer: may-alias dynamic write over As + kept-live read-back.
  // ds_read remat across a may-alias store is illegal -> afr must stay in
  // registers; with no class constraint the allocator uses AGPRs.
  As[(t * 131) & 16383] = (u16)t;
  __syncthreads();
  { u16 rb = As[(t * 67) & 16383]; u32 rv = rb;
    asm volatile("" :: "v"(rv)); }

  f32x4 outacc[4];
#pragma unroll
  for (int a = 0; a < 4; ++a) outacc[a] = (f32x4){0.f, 0.f, 0.f, 0.f};

  const s16x8* __restrict__ Bf = (const s16x8*)A.Bt;
  const int jw = oc * 4 + wid;        // this wave's 16-col group (global j)

  for (int tl = 0; tl < 16; ++tl) {           // tl == d
    s16x8 bfr[8];
#pragma unroll
    for (int ki = 0; ki < 8; ++ki)
      bfr[ki] = Bf[(((tl * J + jw) * 8 + ki) << 6) + lane];

    f32x4 acc[4];
#pragma unroll
    for (int a = 0; a < 4; ++a) acc[a] = (f32x4){0.f, 0.f, 0.f, 0.f};

#pragma unroll
    for (int ki = 0; ki < 8; ++ki)
#pragma unroll
      for (int mi = 0; mi < 4; ++mi)
        acc[mi] = __builtin_amdgcn_mfma_f32_16x16x32_bf16(afr[mi][ki], bfr[ki], acc[mi], 0, 0, 0);

    // fold d: outacc += ew[n,d] * acc
#pragma unroll
    for (int mi = 0; mi < 4; ++mi) {
      int nl = (mi * 16 + quad * 4) >> 3;
      float s = ewS[nl][tl];
#pragma unroll
      for (int r = 0; r < 4; ++r)
        outacc[mi][r] += s * acc[mi][r];
    }
  }

  // epilogue: bias + activation + store (o is wave-uniform branch)
  const int o = jw * 16 + l16;        // global out-col (0..O-1)
#pragma unroll
  for (int mi = 0; mi < 4; ++mi)
#pragma unroll
    for (int r = 0; r < 4; ++r) {
      int row = row0 + mi * 16 + quad * 4 + r;
      int n = row >> 3, b = row & 7;
      float pre = outacc[mi][r] + A.Bias[(size_t)mode * 1000 * O + n * O + o];
      if (is_gate) {
        float sg = 1.f / (1.f + __expf(-pre));
        if (o < 64) {
          float st = A.state[mode][(b * 1000 + n) * 64 + o];
          float zs = sg * st;
          A.ZSt[(size_t)mode * 524288 + (size_t)(b * 64 + o) * 1024 + n] = (u16)f2bf(zs);
          A.AgU[(size_t)mode * 2048000 + (size_t)row * 256 + 16 + o] = (u16)f2bf(zs);
        } else {
          A.Rb[(size_t)mode * 512000 + row * 64 + (o - 64)] = sg;
        }
      } else {
        float hc = tanhf(pre);
        float rr = A.Rb[(size_t)mode * 512000 + row * 64 + o];
        float st = A.state[mode][(b * 1000 + n) * 64 + o];
        A.out[(size_t)mode * 512000 + (b * 1000 + n) * 64 + o] = rr * st + (1.f - rr) * hc;
      }
    }
}

// ---------------------------------------------------------------------------
extern "C" void kernel_launch(void* const* d_in, const int* in_sizes, int n_in,
                              void* d_out, int out_size, void* d_ws, size_t ws_size,
                              hipStream_t stream) {
  const float* x[3]   = {(const float*)d_in[0], (const float*)d_in[1], (const float*)d_in[2]};
  const float* st[3]  = {(const float*)d_in[3], (const float*)d_in[4], (const float*)d_in[5]};
  const float* S[3]   = {(const float*)d_in[6], (const float*)d_in[7], (const float*)d_in[8]};
  const float* emb[3] = {(const float*)d_in[9], (const float*)d_in[10], (const float*)d_in[11]};
  const float* me = (const float*)d_in[12];
  const float* Wg = (const float*)d_in[13];
  const float* Bg = (const float*)d_in[14];
  const float* Wu = (const float*)d_in[15];
  const float* Bu = (const float*)d_in[16];
  float* out = (float*)d_out;

  float* BiG = (float*)d_ws;            // 3*1000*128
  float* BiU = BiG + 384000;            // 3*1000*64
  float* Rb  = BiU + 192000;            // 3*8000*64
  u16* S16 = (u16*)(Rb + 1536000);      // 3*1024*1024
  u16* Xt  = S16 + 3145728;             // 3*640*1024
  u16* T1t = Xt + 1966080;              // 3*640*1024
  u16* ZSt = T1t + 1966080;             // 3*512*1024
  u16* SZ1t= ZSt + 1572864;             // 3*512*1024
  u16* Ag  = SZ1t + 1572864;            // 3*8000*256
  u16* AgU = Ag + 6144000;              // 3*8000*256
  u16* BtG = AgU + 6144000;             // 2048*256
  u16* BtU = BtG + 524288;              // 1024*256

  {
    PrepArgs P;
    for (int m = 0; m < 3; ++m) { P.x[m] = x[m]; P.st[m] = st[m]; P.S[m] = S[m]; }
    P.S16 = S16; P.Xt = Xt; P.Ag = Ag; P.AgU = AgU; P.T1t = T1t; P.ZSt = ZSt; P.SZ1t = SZ1t;
    prep_v<<<8109, 256, 0, stream>>>(P);
  }
  aux_kernel<<<5322, 256, 0, stream>>>(emb[0], emb[1], emb[2], me, Bg, Bu,
                                       Wg, Wu, BiG, BiU, BtG, BtU);

  // cheb1: T1t = Xt @ S^T -> T1t + Ag[80..159] (+AgU x-part)
  {
    ChebArgs2 a;
    for (int m = 0; m < 3; ++m) {
      a.S16[m] = S16 + (size_t)m * 1048576; a.A[m] = Xt + (size_t)m * 655360;
      a.Res[m] = nullptr; a.Yt[m] = T1t + (size_t)m * 655360;
      a.AgA[m] = Ag + (size_t)m * 2048000; a.AgX[m] = AgU + (size_t)m * 2048000;
    }
    cheb_v4<<<dim3(16, 10, 3), 256, 0, stream>>>(a, 80, 80, 1.f, 0.f, 2 | 4);
  }
  // cheb2: T2t = 2*T1t @ S^T - Xt -> Ag[160..239] (+AgU x-part)
  {
    ChebArgs2 a;
    for (int m = 0; m < 3; ++m) {
      a.S16[m] = S16 + (size_t)m * 1048576; a.A[m] = T1t + (size_t)m * 655360;
      a.Res[m] = Xt + (size_t)m * 655360; a.Yt[m] = nullptr;
      a.AgA[m] = Ag + (size_t)m * 2048000; a.AgX[m] = AgU + (size_t)m * 2048000;
    }
    cheb_v4<<<dim3(16, 10, 3), 256, 0, stream>>>(a, 80, 160, 2.f, -1.f, 1 | 4);
  }
  // gate meta: reads Ag; writes ZSt + AgU[16..79] + Rb  (oc split: grid.x=2)
  {
    Meta3Args a;
    a.Ag = Ag; a.Bt = BtG; a.me = me; a.Bias = BiG;
    a.ZSt = ZSt; a.AgU = AgU; a.Rb = Rb; a.out = out;
    for (int m = 0; m < 3; ++m) { a.emb[m] = emb[m]; a.state[m] = st[m]; }
    meta3<<<dim3(2, 125, 3), 256, 0, stream>>>(a, 1, 128);
  }
  // cheb3: SZ1t = ZSt @ S^T -> SZ1t + AgU[96..159]
  {
    ChebArgs2 a;
    for (int m = 0; m < 3; ++m) {
      a.S16[m] = S16 + (size_t)m * 1048576; a.A[m] = ZSt + (size_t)m * 524288;
      a.Res[m] = nullptr; a.Yt[m] = SZ1t + (size_t)m * 524288;
      a.AgA[m] = AgU + (size_t)m * 2048000; a.AgX[m] = nullptr;
    }
    cheb_v4<<<dim3(16, 8, 3), 256, 0, stream>>>(a, 64, 96, 1.f, 0.f, 2);
  }
  // cheb4: SZ2t = 2*SZ1t @ S^T - ZSt -> AgU[176..239]
  {
    ChebArgs2 a;
    for (int m = 0; m < 3; ++m) {
      a.S16[m] = S16 + (size_t)m * 1048576; a.A[m] = SZ1t + (size_t)m * 524288;
      a.Res[m] = ZSt + (size_t)m * 524288; a.Yt[m] = nullptr;
      a.AgA[m] = AgU + (size_t)m * 2048000; a.AgX[m] = nullptr;
    }
    cheb_v4<<<dim3(16, 8, 3), 256, 0, stream>>>(a, 64, 176, 2.f, -1.f, 1);
  }
  // update meta: reads AgU; writes out
  {
    Meta3Args a;
    a.Ag = AgU; a.Bt = BtU; a.me = me; a.Bias = BiU;
    a.ZSt = ZSt; a.AgU = AgU; a.Rb = Rb; a.out = out;
    for (int m = 0; m < 3; ++m) { a.emb[m] = emb[m]; a.state[m] = st[m]; }
    meta3<<<dim3(1, 125, 3), 256, 0, stream>>>(a, 0, 64);
  }
}

// Round 10
// 292.650 us; speedup vs baseline: 1.0025x; 1.0025x over previous
//
#include <hip/hip_runtime.h>
#include <math.h>

// ---------------------------------------------------------------------------
// HimNet multimode v13. B=8,N=1000,CIN=16,H=64,D=16,K=3,XIN=80,K*XIN=240,2H=128
//
// v13 = v11 + T14 reg-staged async B pipeline in meta3:
//   per d-tile: ds_write tile tl from 32 VGPRs -> issue global loads for
//   tl+1 -> barrier -> compute -> barrier. Loads are in flight across the
//   whole compute phase; compiler inserts the vmcnt wait before the next
//   ds_write (no counted-vmcnt asm - v5/v10's failure mode avoided).
// Rationale: v6's 52us is latency*concurrency bound (drain-then-compute
// duty cycle; Little: ~128 inflight x 16B / 200cy = 10B/cy/CU = observed
// 7.3TB/s). Reg-staging keeps loads in flight during compute.
// VGPR: afr 64(AGPR) + br 32 + acc 32 + misc -> launch_bounds(256,3).
// Closed lines: afr[4][8] register residency (v8/v9/v12 all failed);
// counted-vmcnt glds pipelines (v5/v10); "+v" class pins (v9).
// ---------------------------------------------------------------------------

typedef __attribute__((ext_vector_type(8))) short s16x8;
typedef __attribute__((ext_vector_type(4))) float f32x4;
typedef unsigned short u16;
typedef unsigned int u32;
typedef unsigned long long u64;

__device__ __forceinline__ u32 f2bf(float f) {
  union { float f; u32 u; } v; v.f = f;
  return (v.u + 0x7FFFu + ((v.u >> 16) & 1u)) >> 16;  // RNE
}
__device__ __forceinline__ float bf2f(u16 h) {
  union { u32 u; float f; } v; v.u = (u32)h << 16; return v.f;
}
__device__ __forceinline__ u64 pk4(float a, float b, float c, float d) {
  return (u64)f2bf(a) | ((u64)f2bf(b) << 16) | ((u64)f2bf(c) << 32) |
         ((u64)f2bf(d) << 48);
}
__device__ __forceinline__ void glds16(const u16* g, u16* l) {
  __builtin_amdgcn_global_load_lds(
      (const __attribute__((address_space(1))) void*)g,
      (__attribute__((address_space(3))) void*)l, 16, 0, 0);
}

// ---------------------------------------------------------------------------
// prep_v: vectorized 4 elems/thread (v11).
// ---------------------------------------------------------------------------
#define E0 3145728
#define E1 1966080
#define E2 1920000
#define E3 384000
#define E4 384000
#define E5 384000
#define E6 119808
// total = 8303616 elems = 2075904 threads = 8109 * 256

struct PrepArgs {
  const float* x[3]; const float* st[3]; const float* S[3];
  u16 *S16, *Xt, *Ag, *AgU, *T1t, *ZSt, *SZ1t;
};

__global__ void prep_v(PrepArgs P) {
  long idx = ((long)blockIdx.x * 256 + threadIdx.x) * 4;
  if (idx < E0) {  // S16 incl pads: 4 consecutive k, same n
    int m = (int)(idx >> 20); int rem = (int)(idx & 1048575);
    int n = rem >> 10, k = rem & 1023;
    u64 pv = 0;
    if (n < 1000 && k < 1000) {
      f32x4 v = *(const f32x4*)&P.S[m][n * 1000 + k];
      pv = pk4(v[0], v[1], v[2], v[3]);
    }
    *(u64*)&P.S16[(size_t)m * 1048576 + rem] = pv; return;
  }
  idx -= E0;
  if (idx < E1) {  // Xt: 4 consecutive nn, same col
    int m = (int)(idx / 655360); int rem = (int)(idx % 655360);
    int col = rem >> 10, nn = rem & 1023;
    int b = col / 80, c = col % 80;
    u64 pv = 0;
    if (nn < 1000) {
      float f[4];
#pragma unroll
      for (int j = 0; j < 4; ++j)
        f[j] = (c < 16) ? P.x[m][(b * 1000 + nn + j) * 16 + c]
                        : P.st[m][(b * 1000 + nn + j) * 64 + c - 16];
      pv = pk4(f[0], f[1], f[2], f[3]);
    }
    *(u64*)&P.Xt[(size_t)m * 655360 + rem] = pv; return;
  }
  idx -= E1;
  if (idx < E2) {  // Ag kc0: 4 consecutive c, same r
    int m = (int)(idx / 640000); int rem = (int)(idx % 640000);
    int r = rem / 80, c = rem % 80;
    int n = r >> 3, b = r & 7;
    f32x4 v = (c < 16) ? *(const f32x4*)&P.x[m][(b * 1000 + n) * 16 + c]
                       : *(const f32x4*)&P.st[m][(b * 1000 + n) * 64 + c - 16];
    *(u64*)&P.Ag[(size_t)m * 2048000 + (size_t)r * 256 + c] =
        pk4(v[0], v[1], v[2], v[3]);
    return;
  }
  idx -= E2;
  if (idx < E3) {  // Ag K-pad 240..255
    int m = (int)(idx / 128000); int rem = (int)(idx % 128000);
    int r = rem / 16, c = 240 + rem % 16;
    *(u64*)&P.Ag[(size_t)m * 2048000 + (size_t)r * 256 + c] = 0; return;
  }
  idx -= E3;
  if (idx < E4) {  // AgU kc0 x-part (cols 0..15)
    int m = (int)(idx / 128000); int rem = (int)(idx % 128000);
    int r = rem / 16, c = rem % 16;
    int n = r >> 3, b = r & 7;
    f32x4 v = *(const f32x4*)&P.x[m][(b * 1000 + n) * 16 + c];
    *(u64*)&P.AgU[(size_t)m * 2048000 + (size_t)r * 256 + c] =
        pk4(v[0], v[1], v[2], v[3]);
    return;
  }
  idx -= E4;
  if (idx < E5) {  // AgU K-pad
    int m = (int)(idx / 128000); int rem = (int)(idx % 128000);
    int r = rem / 16, c = 240 + rem % 16;
    *(u64*)&P.AgU[(size_t)m * 2048000 + (size_t)r * 256 + c] = 0; return;
  }
  idx -= E5;
  if (idx < E6) {  // n-pad rows (k=1000..1023) of T1t/ZSt/SZ1t
    int m = (int)(idx / 39936); int rem = (int)(idx % 39936);
    if (rem < 15360) { int col = rem / 24, j = rem % 24;
      *(u64*)&P.T1t[(size_t)m * 655360 + col * 1024 + 1000 + j] = 0; }
    else if (rem < 27648) { int e = rem - 15360; int col = e / 24, j = e % 24;
      *(u64*)&P.ZSt[(size_t)m * 524288 + col * 1024 + 1000 + j] = 0; }
    else { int e = rem - 27648; int col = e / 24, j = e % 24;
      *(u64*)&P.SZ1t[(size_t)m * 524288 + col * 1024 + 1000 + j] = 0; }
    return;
  }
}

// ---------------------------------------------------------------------------
// aux: BiG + BiU + packW d-major (v6/v11 layout: Bt[(d*O+o)][k]).
// ---------------------------------------------------------------------------
__global__ void aux_kernel(const float* __restrict__ e0, const float* __restrict__ e1,
                           const float* __restrict__ e2, const float* __restrict__ me,
                           const float* __restrict__ Bg, const float* __restrict__ Bu,
                           const float* __restrict__ Wg, const float* __restrict__ Wu,
                           float* __restrict__ BiG, float* __restrict__ BiU,
                           u16* __restrict__ BtG, u16* __restrict__ BtU) {
  int idx = blockIdx.x * blockDim.x + threadIdx.x;
  if (idx < 384000) {        // BiG[mode][n*128+o]
    int mode = idx / 128000, rem = idx % 128000;
    int n = rem >> 7, o = rem & 127;
    const float* emb = (mode == 0) ? e0 : (mode == 1) ? e1 : e2;
    float s = 0.f;
#pragma unroll
    for (int d = 0; d < 16; ++d)
      s += emb[n * 16 + d] * me[mode * 16 + d] * Bg[d * 128 + o];
    BiG[idx] = s; return;
  }
  idx -= 384000;
  if (idx < 192000) {        // BiU[mode][n*64+o]
    int mode = idx / 64000, rem = idx % 64000;
    int n = rem >> 6, o = rem & 63;
    const float* emb = (mode == 0) ? e0 : (mode == 1) ? e1 : e2;
    float s = 0.f;
#pragma unroll
    for (int d = 0; d < 16; ++d)
      s += emb[n * 16 + d] * me[mode * 16 + d] * Bu[d * 64 + o];
    BiU[idx] = s; return;
  }
  idx -= 192000;
  if (idx < 524288) {        // BtG d-major
    int col = idx >> 8, k = idx & 255;
    int d = col >> 7, o = col & 127;
    BtG[idx] = (k < 240) ? (u16)f2bf(Wg[d * 30720 + k * 128 + o]) : (u16)0;
    return;
  }
  idx -= 524288;
  {                          // BtU d-major
    int col = idx >> 8, k = idx & 255;
    int d = col >> 6, o = col & 63;
    BtU[idx] = (k < 240) ? (u16)f2bf(Wu[d * 15360 + k * 64 + o]) : (u16)0;
  }
}

// ---------------------------------------------------------------------------
// cheb_v4: unchanged.
// ---------------------------------------------------------------------------
struct ChebArgs2 {
  const u16* S16[3]; const u16* A[3]; const u16* Res[3];
  u16* Yt[3]; u16* AgA[3]; u16* AgX[3];
};

__global__ __launch_bounds__(256, 2) void cheb_v4(ChebArgs2 g, int fdiv, int agbase,
                                                  float alpha, float beta, int flags) {
  const int mode = blockIdx.z;
  const u16* __restrict__ Ab = g.A[mode];
  const u16* __restrict__ Sb = g.S16[mode];

  __shared__ u16 As[64 * 64];
  __shared__ u16 Bs[64 * 64];

  const int t = threadIdx.x;
  const int row0 = blockIdx.y * 64, n0 = blockIdx.x * 64;
  const int lane = t & 63, wid = t >> 6;
  const int l16 = lane & 15, quad = lane >> 4;
  const int wy = (wid >> 1) * 32, wx = (wid & 1) * 32;

  f32x4 acc[2][2];
#pragma unroll
  for (int a = 0; a < 2; ++a)
#pragma unroll
    for (int b = 0; b < 2; ++b) acc[a][b] = (f32x4){0.f, 0.f, 0.f, 0.f};

  for (int k0 = 0; k0 < 1024; k0 += 64) {
#pragma unroll
    for (int p = 0; p < 2; ++p) {  // A: 64x64 = 512 chunks
      int idx = p * 256 + t; int row = idx >> 3; int cs = (idx & 7) ^ (row & 7);
      glds16(Ab + (size_t)(row0 + row) * 1024 + k0 + cs * 8, &As[idx * 8]);
    }
#pragma unroll
    for (int p = 0; p < 2; ++p) {  // B: 64x64 = 512 chunks
      int idx = p * 256 + t; int row = idx >> 3; int cs = (idx & 7) ^ (row & 7);
      glds16(Sb + (size_t)(n0 + row) * 1024 + k0 + cs * 8, &Bs[idx * 8]);
    }
    __syncthreads();
    s16x8 af[2][2], bf[2][2];
#pragma unroll
    for (int mi = 0; mi < 2; ++mi) {
      int row = wy + mi * 16 + l16;
#pragma unroll
      for (int ks = 0; ks < 2; ++ks) {
        int cl = (ks * 4 + quad) ^ (row & 7);
        af[mi][ks] = *(const s16x8*)&As[row * 64 + cl * 8];
      }
    }
#pragma unroll
    for (int ni = 0; ni < 2; ++ni) {
      int row = wx + ni * 16 + l16;
#pragma unroll
      for (int ks = 0; ks < 2; ++ks) {
        int cl = (ks * 4 + quad) ^ (row & 7);
        bf[ni][ks] = *(const s16x8*)&Bs[row * 64 + cl * 8];
      }
    }
#pragma unroll
    for (int ks = 0; ks < 2; ++ks)
#pragma unroll
      for (int mi = 0; mi < 2; ++mi)
#pragma unroll
        for (int ni = 0; ni < 2; ++ni)
          acc[mi][ni] = __builtin_amdgcn_mfma_f32_16x16x32_bf16(af[mi][ks], bf[ni][ks], acc[mi][ni], 0, 0, 0);
    __syncthreads();
  }

#pragma unroll
  for (int mi = 0; mi < 2; ++mi) {
    int frow0 = row0 + wy + mi * 16 + quad * 4;
    int b = frow0 / fdiv, c0 = frow0 - b * fdiv;
#pragma unroll
    for (int ni = 0; ni < 2; ++ni) {
      int n = n0 + wx + ni * 16 + l16;
      if (n < 1000) {
        u16 pk[4];
#pragma unroll
        for (int r = 0; r < 4; ++r) {
          float v = alpha * acc[mi][ni][r];
          if (flags & 1) v += beta * bf2f(g.Res[mode][(size_t)(frow0 + r) * 1024 + n]);
          u16 h = (u16)f2bf(v);
          pk[r] = h;
          if (flags & 2) g.Yt[mode][(size_t)(frow0 + r) * 1024 + n] = h;
        }
        u64 pv = (u64)pk[0] | ((u64)pk[1] << 16) | ((u64)pk[2] << 32) | ((u64)pk[3] << 48);
        *(u64*)&g.AgA[mode][(size_t)(n * 8 + b) * 256 + agbase + c0] = pv;
        if ((flags & 4) && c0 < 16)
          *(u64*)&g.AgX[mode][(size_t)(n * 8 + b) * 256 + agbase + c0] = pv;
      }
    }
  }
}

// ---------------------------------------------------------------------------
// meta3 v13: v6 structure + T14 reg-staged async B.
// Per tile: ds_write tl (from br regs) -> issue global loads tl+1 into br
// -> barrier -> compute tl -> barrier. Compiler manages waitcnts; loads fly
// across the compute phase. afr[2][8] AGPR-resident (v6 mechanism).
// ---------------------------------------------------------------------------
struct Meta3Args {
  const u16* Ag;        // [3][8000][256]
  const u16* Bt;        // [O*16][256] d-major
  const float* emb[3];
  const float* me;
  const float* Bias;    // [3][1000][O]
  const float* state[3];
  u16* ZSt;             // [3][512][1024]
  u16* AgU;             // [3][8000][256]
  float* Rb;            // [3][8000][64]
  float* out;
};

__global__ __launch_bounds__(256, 3) void meta3(Meta3Args A, int is_gate, int O) {
  const int mode = blockIdx.z;
  const int row0 = blockIdx.y * 64;
  const int n0 = row0 >> 3;
  const int oc = blockIdx.x;          // out-col block: gate 0/1, update 0
  const int ocbase = oc * 64;

  __shared__ u16 Bs[64 * 256];   // 32KB: A-stage in prologue, then B tiles
  __shared__ float ewS[8][17];

  const int t = threadIdx.x;
  if (t < 128) {
    int nl = t >> 4, d = t & 15;
    ewS[nl][d] = A.emb[mode][(n0 + nl) * 16 + d] * A.me[mode * 16 + d];
  }

  const int lane = t & 63, wid = t >> 6;
  const int l16 = lane & 15, quad = lane >> 4;
  const int wy = (wid >> 1) * 32, wx = (wid & 1) * 32;
  const u16* Agm = A.Ag + (size_t)mode * 2048000;

  // prologue: stage A rows [row0,row0+64) x K256 into Bs, hoist to registers
#pragma unroll
  for (int p = 0; p < 8; ++p) {
    int idx = p * 256 + t; int row = idx >> 5; int cs = (idx & 31) ^ (row & 7);
    glds16(Agm + (size_t)(row0 + row) * 256 + cs * 8, &Bs[idx * 8]);
  }
  __syncthreads();

  s16x8 afr[2][8];   // AGPR-resident (unified file); no class constraints
#pragma unroll
  for (int mi = 0; mi < 2; ++mi) {
    int row = wy + mi * 16 + l16;
#pragma unroll
    for (int ki = 0; ki < 8; ++ki) {
      int cl = (ki * 4 + quad) ^ (row & 7);
      afr[mi][ki] = *(const s16x8*)&Bs[row * 256 + cl * 8];
    }
  }
  __syncthreads();   // hoist reads retired before Bs is overwritten

  // reg-stage B tile 0 (loop-invariant per-thread offsets)
  const u16* Bt0 = A.Bt + (size_t)ocbase * 256;
  const size_t tstride = (size_t)O * 256;    // elements per d-tile
  s16x8 br[8];
#pragma unroll
  for (int p = 0; p < 8; ++p) {
    int idx = p * 256 + t; int row = idx >> 5; int cs = (idx & 31) ^ (row & 7);
    br[p] = *(const s16x8*)(Bt0 + (size_t)row * 256 + cs * 8);
  }

  f32x4 outacc[2][2];
#pragma unroll
  for (int a = 0; a < 2; ++a)
#pragma unroll
    for (int b = 0; b < 2; ++b) outacc[a][b] = (f32x4){0.f, 0.f, 0.f, 0.f};

  for (int tl = 0; tl < 16; ++tl) {           // tl == d
    // write tile tl to LDS (compiler inserts vmcnt wait for br loads)
#pragma unroll
    for (int p = 0; p < 8; ++p) {
      int idx = p * 256 + t;
      *(s16x8*)&Bs[idx * 8] = br[p];
    }
    // issue loads for tile tl+1; they stay in flight during compute of tl
    if (tl + 1 < 16) {
      const u16* src = Bt0 + (size_t)(tl + 1) * tstride;
#pragma unroll
      for (int p = 0; p < 8; ++p) {
        int idx = p * 256 + t; int row = idx >> 5; int cs = (idx & 31) ^ (row & 7);
        br[p] = *(const s16x8*)(src + (size_t)row * 256 + cs * 8);
      }
    }
    __syncthreads();   // B tile tl visible

    f32x4 acc[2][2];
#pragma unroll
    for (int a = 0; a < 2; ++a)
#pragma unroll
      for (int b = 0; b < 2; ++b) acc[a][b] = (f32x4){0.f, 0.f, 0.f, 0.f};

#pragma unroll
    for (int ki = 0; ki < 8; ++ki) {
      s16x8 bfr[2];
#pragma unroll
      for (int ni = 0; ni < 2; ++ni) {
        int row = wx + ni * 16 + l16;
        int cl = (ki * 4 + quad) ^ (row & 7);
        bfr[ni] = *(const s16x8*)&Bs[row * 256 + cl * 8];
      }
#pragma unroll
      for (int mi = 0; mi < 2; ++mi)
#pragma unroll
        for (int ni = 0; ni < 2; ++ni)
          acc[mi][ni] = __builtin_amdgcn_mfma_f32_16x16x32_bf16(afr[mi][ki], bfr[ni], acc[mi][ni], 0, 0, 0);
    }

    // fold d: outacc += ew[n,d] * acc
#pragma unroll
    for (int mi = 0; mi < 2; ++mi) {
      int nl = (wy + mi * 16 + quad * 4) >> 3;
      float s = ewS[nl][tl];
#pragma unroll
      for (int ni = 0; ni < 2; ++ni)
#pragma unroll
        for (int r = 0; r < 4; ++r)
          outacc[mi][ni][r] += s * acc[mi][ni][r];
    }
    __syncthreads();   // Bs reads retired before next tile's write
  }

  // epilogue: bias + activation + store, straight from registers
#pragma unroll
  for (int mi = 0; mi < 2; ++mi)
#pragma unroll
    for (int ni = 0; ni < 2; ++ni)
#pragma unroll
      for (int r = 0; r < 4; ++r) {
        int row = row0 + wy + mi * 16 + quad * 4 + r;
        int n = row >> 3, b = row & 7;
        int o = ocbase + wx + ni * 16 + l16;
        float pre = outacc[mi][ni][r] + A.Bias[(size_t)mode * 1000 * O + n * O + o];
        if (is_gate) {
          float sg = 1.f / (1.f + __expf(-pre));
          if (o < 64) {
            float st = A.state[mode][(b * 1000 + n) * 64 + o];
            float zs = sg * st;
            A.ZSt[(size_t)mode * 524288 + (size_t)(b * 64 + o) * 1024 + n] = (u16)f2bf(zs);
            A.AgU[(size_t)mode * 2048000 + (size_t)row * 256 + 16 + o] = (u16)f2bf(zs);
          } else {
            A.Rb[(size_t)mode * 512000 + row * 64 + (o - 64)] = sg;
          }
        } else {
          float hc = tanhf(pre);
          float rr = A.Rb[(size_t)mode * 512000 + row * 64 + o];
          float st = A.state[mode][(b * 1000 + n) * 64 + o];
          A.out[(size_t)mode * 512000 + (b * 1000 + n) * 64 + o] = rr * st + (1.f - rr) * hc;
        }
      }
}

// ---------------------------------------------------------------------------
extern "C" void kernel_launch(void* const* d_in, const int* in_sizes, int n_in,
                              void* d_out, int out_size, void* d_ws, size_t ws_size,
                              hipStream_t stream) {
  const float* x[3]   = {(const float*)d_in[0], (const float*)d_in[1], (const float*)d_in[2]};
  const float* st[3]  = {(const float*)d_in[3], (const float*)d_in[4], (const float*)d_in[5]};
  const float* S[3]   = {(const float*)d_in[6], (const float*)d_in[7], (const float*)d_in[8]};
  const float* emb[3] = {(const float*)d_in[9], (const float*)d_in[10], (const float*)d_in[11]};
  const float* me = (const float*)d_in[12];
  const float* Wg = (const float*)d_in[13];
  const float* Bg = (const float*)d_in[14];
  const float* Wu = (const float*)d_in[15];
  const float* Bu = (const float*)d_in[16];
  float* out = (float*)d_out;

  float* BiG = (float*)d_ws;            // 3*1000*128
  float* BiU = BiG + 384000;            // 3*1000*64
  float* Rb  = BiU + 192000;            // 3*8000*64
  u16* S16 = (u16*)(Rb + 1536000);      // 3*1024*1024
  u16* Xt  = S16 + 3145728;             // 3*640*1024
  u16* T1t = Xt + 1966080;              // 3*640*1024
  u16* ZSt = T1t + 1966080;             // 3*512*1024
  u16* SZ1t= ZSt + 1572864;             // 3*512*1024
  u16* Ag  = SZ1t + 1572864;            // 3*8000*256
  u16* AgU = Ag + 6144000;              // 3*8000*256
  u16* BtG = AgU + 6144000;             // 2048*256
  u16* BtU = BtG + 524288;              // 1024*256

  {
    PrepArgs P;
    for (int m = 0; m < 3; ++m) { P.x[m] = x[m]; P.st[m] = st[m]; P.S[m] = S[m]; }
    P.S16 = S16; P.Xt = Xt; P.Ag = Ag; P.AgU = AgU; P.T1t = T1t; P.ZSt = ZSt; P.SZ1t = SZ1t;
    prep_v<<<8109, 256, 0, stream>>>(P);
  }
  aux_kernel<<<5322, 256, 0, stream>>>(emb[0], emb[1], emb[2], me, Bg, Bu,
                                       Wg, Wu, BiG, BiU, BtG, BtU);

  // cheb1: T1t = Xt @ S^T -> T1t + Ag[80..159] (+AgU x-part)
  {
    ChebArgs2 a;
    for (int m = 0; m < 3; ++m) {
      a.S16[m] = S16 + (size_t)m * 1048576; a.A[m] = Xt + (size_t)m * 655360;
      a.Res[m] = nullptr; a.Yt[m] = T1t + (size_t)m * 655360;
      a.AgA[m] = Ag + (size_t)m * 2048000; a.AgX[m] = AgU + (size_t)m * 2048000;
    }
    cheb_v4<<<dim3(16, 10, 3), 256, 0, stream>>>(a, 80, 80, 1.f, 0.f, 2 | 4);
  }
  // cheb2: T2t = 2*T1t @ S^T - Xt -> Ag[160..239] (+AgU x-part)
  {
    ChebArgs2 a;
    for (int m = 0; m < 3; ++m) {
      a.S16[m] = S16 + (size_t)m * 1048576; a.A[m] = T1t + (size_t)m * 655360;
      a.Res[m] = Xt + (size_t)m * 655360; a.Yt[m] = nullptr;
      a.AgA[m] = Ag + (size_t)m * 2048000; a.AgX[m] = AgU + (size_t)m * 2048000;
    }
    cheb_v4<<<dim3(16, 10, 3), 256, 0, stream>>>(a, 80, 160, 2.f, -1.f, 1 | 4);
  }
  // gate meta: reads Ag; writes ZSt + AgU[16..79] + Rb  (oc split: grid.x=2)
  {
    Meta3Args a;
    a.Ag = Ag; a.Bt = BtG; a.me = me; a.Bias = BiG;
    a.ZSt = ZSt; a.AgU = AgU; a.Rb = Rb; a.out = out;
    for (int m = 0; m < 3; ++m) { a.emb[m] = emb[m]; a.state[m] = st[m]; }
    meta3<<<dim3(2, 125, 3), 256, 0, stream>>>(a, 1, 128);
  }
  // cheb3: SZ1t = ZSt @ S^T -> SZ1t + AgU[96..159]
  {
    ChebArgs2 a;
    for (int m = 0; m < 3; ++m) {
      a.S16[m] = S16 + (size_t)m * 1048576; a.A[m] = ZSt + (size_t)m * 524288;
      a.Res[m] = nullptr; a.Yt[m] = SZ1t + (size_t)m * 524288;
      a.AgA[m] = AgU + (size_t)m * 2048000; a.AgX[m] = nullptr;
    }
    cheb_v4<<<dim3(16, 8, 3), 256, 0, stream>>>(a, 64, 96, 1.f, 0.f, 2);
  }
  // cheb4: SZ2t = 2*SZ1t @ S^T - ZSt -> AgU[176..239]
  {
    ChebArgs2 a;
    for (int m = 0; m < 3; ++m) {
      a.S16[m] = S16 + (size_t)m * 1048576; a.A[m] = SZ1t + (size_t)m * 524288;
      a.Res[m] = ZSt + (size_t)m * 524288; a.Yt[m] = nullptr;
      a.AgA[m] = AgU + (size_t)m * 2048000; a.AgX[m] = nullptr;
    }
    cheb_v4<<<dim3(16, 8, 3), 256, 0, stream>>>(a, 64, 176, 2.f, -1.f, 1);
  }
  // update meta: reads AgU; writes out
  {
    Meta3Args a;
    a.Ag = AgU; a.Bt = BtU; a.me = me; a.Bias = BiU;
    a.ZSt = ZSt; a.AgU = AgU; a.Rb = Rb; a.out = out;
    for (int m = 0; m < 3; ++m) { a.emb[m] = emb[m]; a.state[m] = st[m]; }
    meta3<<<dim3(1, 125, 3), 256, 0, stream>>>(a, 0, 64);
  }
}

// Round 11
// 257.317 us; speedup vs baseline: 1.1402x; 1.1373x over previous
//
#include <hip/hip_runtime.h>
#include <math.h>

// ---------------------------------------------------------------------------
// HimNet multimode v14. B=8,N=1000,CIN=16,H=64,D=16,K=3,XIN=80,K*XIN=240,2H=128
//
// v14 = v11 (meta3 = proven v6 structure, 52.5us) +
//   - cheb BK 64->128: 8 barriered k-steps instead of 16 (cheb is
//     grid-limited ~1.9 blocks/CU -> chain-bound like meta3; halve the
//     per-block drain count). LDS 32.5KB, af/bf[2][4].
//   - prep_v + aux merged into one launch (independent inputs).
// Closed lines (do not revisit): meta3 pipelining — counted-vmcnt glds
// (v5/v10: L2-thrash/occupancy), afr[4][8] residency (v8/v9/v12),
// "+v" pins (v9 spill), reg-staged T14 (v13: __syncthreads drains vmcnt,
// occupancy loss 4->3 fully explains the 72us).
// ---------------------------------------------------------------------------

typedef __attribute__((ext_vector_type(8))) short s16x8;
typedef __attribute__((ext_vector_type(4))) float f32x4;
typedef unsigned short u16;
typedef unsigned int u32;
typedef unsigned long long u64;

__device__ __forceinline__ u32 f2bf(float f) {
  union { float f; u32 u; } v; v.f = f;
  return (v.u + 0x7FFFu + ((v.u >> 16) & 1u)) >> 16;  // RNE
}
__device__ __forceinline__ float bf2f(u16 h) {
  union { u32 u; float f; } v; v.u = (u32)h << 16; return v.f;
}
__device__ __forceinline__ u64 pk4(float a, float b, float c, float d) {
  return (u64)f2bf(a) | ((u64)f2bf(b) << 16) | ((u64)f2bf(c) << 32) |
         ((u64)f2bf(d) << 48);
}
__device__ __forceinline__ void glds16(const u16* g, u16* l) {
  __builtin_amdgcn_global_load_lds(
      (const __attribute__((address_space(1))) void*)g,
      (__attribute__((address_space(3))) void*)l, 16, 0, 0);
}

// ---------------------------------------------------------------------------
// prep_aux: prep (4 elems/thread) + aux (1 elem/thread) in one launch.
// prep regions (elem counts, all %4==0): S16, Xt, Ag kc0, Ag K-pad, AgU x,
// AgU K-pad, n-pad rows. aux: BiG, BiU, BtG d-major, BtU d-major.
// ---------------------------------------------------------------------------
#define E0 3145728
#define E1 1966080
#define E2 1920000
#define E3 384000
#define E4 384000
#define E5 384000
#define E6 119808
// prep total = 8303616 elems = 2075904 threads; aux total = 1362432 threads
// grid = 8109 + 5322 = 13431 blocks of 256

struct PrepAuxArgs {
  const float* x[3]; const float* st[3]; const float* S[3];
  u16 *S16, *Xt, *Ag, *AgU, *T1t, *ZSt, *SZ1t;
  const float *e0, *e1, *e2, *me, *Bg, *Bu, *Wg, *Wu;
  float *BiG, *BiU; u16 *BtG, *BtU;
};

__global__ void prep_aux(PrepAuxArgs P) {
  long tid = (long)blockIdx.x * 256 + threadIdx.x;
  if (tid < 2075904) {        // ---- prep path: 4 elems ----
    long idx = tid * 4;
    if (idx < E0) {  // S16 incl pads: 4 consecutive k, same n
      int m = (int)(idx >> 20); int rem = (int)(idx & 1048575);
      int n = rem >> 10, k = rem & 1023;
      u64 pv = 0;
      if (n < 1000 && k < 1000) {
        f32x4 v = *(const f32x4*)&P.S[m][n * 1000 + k];
        pv = pk4(v[0], v[1], v[2], v[3]);
      }
      *(u64*)&P.S16[(size_t)m * 1048576 + rem] = pv; return;
    }
    idx -= E0;
    if (idx < E1) {  // Xt: 4 consecutive nn, same col
      int m = (int)(idx / 655360); int rem = (int)(idx % 655360);
      int col = rem >> 10, nn = rem & 1023;
      int b = col / 80, c = col % 80;
      u64 pv = 0;
      if (nn < 1000) {
        float f[4];
#pragma unroll
        for (int j = 0; j < 4; ++j)
          f[j] = (c < 16) ? P.x[m][(b * 1000 + nn + j) * 16 + c]
                          : P.st[m][(b * 1000 + nn + j) * 64 + c - 16];
        pv = pk4(f[0], f[1], f[2], f[3]);
      }
      *(u64*)&P.Xt[(size_t)m * 655360 + rem] = pv; return;
    }
    idx -= E1;
    if (idx < E2) {  // Ag kc0: 4 consecutive c, same r
      int m = (int)(idx / 640000); int rem = (int)(idx % 640000);
      int r = rem / 80, c = rem % 80;
      int n = r >> 3, b = r & 7;
      f32x4 v = (c < 16) ? *(const f32x4*)&P.x[m][(b * 1000 + n) * 16 + c]
                         : *(const f32x4*)&P.st[m][(b * 1000 + n) * 64 + c - 16];
      *(u64*)&P.Ag[(size_t)m * 2048000 + (size_t)r * 256 + c] =
          pk4(v[0], v[1], v[2], v[3]);
      return;
    }
    idx -= E2;
    if (idx < E3) {  // Ag K-pad 240..255
      int m = (int)(idx / 128000); int rem = (int)(idx % 128000);
      int r = rem / 16, c = 240 + rem % 16;
      *(u64*)&P.Ag[(size_t)m * 2048000 + (size_t)r * 256 + c] = 0; return;
    }
    idx -= E3;
    if (idx < E4) {  // AgU kc0 x-part (cols 0..15)
      int m = (int)(idx / 128000); int rem = (int)(idx % 128000);
      int r = rem / 16, c = rem % 16;
      int n = r >> 3, b = r & 7;
      f32x4 v = *(const f32x4*)&P.x[m][(b * 1000 + n) * 16 + c];
      *(u64*)&P.AgU[(size_t)m * 2048000 + (size_t)r * 256 + c] =
          pk4(v[0], v[1], v[2], v[3]);
      return;
    }
    idx -= E4;
    if (idx < E5) {  // AgU K-pad
      int m = (int)(idx / 128000); int rem = (int)(idx % 128000);
      int r = rem / 16, c = 240 + rem % 16;
      *(u64*)&P.AgU[(size_t)m * 2048000 + (size_t)r * 256 + c] = 0; return;
    }
    idx -= E5;
    if (idx < E6) {  // n-pad rows (k=1000..1023) of T1t/ZSt/SZ1t
      int m = (int)(idx / 39936); int rem = (int)(idx % 39936);
      if (rem < 15360) { int col = rem / 24, j = rem % 24;
        *(u64*)&P.T1t[(size_t)m * 655360 + col * 1024 + 1000 + j] = 0; }
      else if (rem < 27648) { int e = rem - 15360; int col = e / 24, j = e % 24;
        *(u64*)&P.ZSt[(size_t)m * 524288 + col * 1024 + 1000 + j] = 0; }
      else { int e = rem - 27648; int col = e / 24, j = e % 24;
        *(u64*)&P.SZ1t[(size_t)m * 524288 + col * 1024 + 1000 + j] = 0; }
      return;
    }
    return;
  }
  // ---- aux path: 1 elem ----
  int idx = (int)(tid - 2075904);
  if (idx < 384000) {        // BiG[mode][n*128+o]
    int mode = idx / 128000, rem = idx % 128000;
    int n = rem >> 7, o = rem & 127;
    const float* emb = (mode == 0) ? P.e0 : (mode == 1) ? P.e1 : P.e2;
    float s = 0.f;
#pragma unroll
    for (int d = 0; d < 16; ++d)
      s += emb[n * 16 + d] * P.me[mode * 16 + d] * P.Bg[d * 128 + o];
    P.BiG[idx] = s; return;
  }
  idx -= 384000;
  if (idx < 192000) {        // BiU[mode][n*64+o]
    int mode = idx / 64000, rem = idx % 64000;
    int n = rem >> 6, o = rem & 63;
    const float* emb = (mode == 0) ? P.e0 : (mode == 1) ? P.e1 : P.e2;
    float s = 0.f;
#pragma unroll
    for (int d = 0; d < 16; ++d)
      s += emb[n * 16 + d] * P.me[mode * 16 + d] * P.Bu[d * 64 + o];
    P.BiU[idx] = s; return;
  }
  idx -= 192000;
  if (idx < 524288) {        // BtG d-major: [(d*128+o)][k]
    int col = idx >> 8, k = idx & 255;
    int d = col >> 7, o = col & 127;
    P.BtG[idx] = (k < 240) ? (u16)f2bf(P.Wg[d * 30720 + k * 128 + o]) : (u16)0;
    return;
  }
  idx -= 524288;
  if (idx < 262144) {        // BtU d-major: [(d*64+o)][k]
    int col = idx >> 8, k = idx & 255;
    int d = col >> 6, o = col & 63;
    P.BtU[idx] = (k < 240) ? (u16)f2bf(P.Wu[d * 15360 + k * 64 + o]) : (u16)0;
  }
}

// ---------------------------------------------------------------------------
// cheb_v5: D[f][n] = alpha*sum_k A[f][k]*S16[n][k] (+beta*Res[f][n])
// Tile 64(f) x 64(n), BK=128 (8 barriered k-steps, was 16 at BK=64).
// 256 thr = 4 waves in 2x2 grid (32x32 each). glds staging, XOR chunk
// swizzle cs = (j)^(row&7) within 16 chunks/row.
// flags: 1=hasRes, 2=hasY, 4=hasAgX
// ---------------------------------------------------------------------------
struct ChebArgs2 {
  const u16* S16[3]; const u16* A[3]; const u16* Res[3];
  u16* Yt[3]; u16* AgA[3]; u16* AgX[3];
};

__global__ __launch_bounds__(256, 2) void cheb_v5(ChebArgs2 g, int fdiv, int agbase,
                                                  float alpha, float beta, int flags) {
  const int mode = blockIdx.z;
  const u16* __restrict__ Ab = g.A[mode];
  const u16* __restrict__ Sb = g.S16[mode];

  __shared__ u16 As[64 * 128];   // 16KB
  __shared__ u16 Bs[64 * 128];   // 16KB

  const int t = threadIdx.x;
  const int row0 = blockIdx.y * 64, n0 = blockIdx.x * 64;
  const int lane = t & 63, wid = t >> 6;
  const int l16 = lane & 15, quad = lane >> 4;
  const int wy = (wid >> 1) * 32, wx = (wid & 1) * 32;

  f32x4 acc[2][2];
#pragma unroll
  for (int a = 0; a < 2; ++a)
#pragma unroll
    for (int b = 0; b < 2; ++b) acc[a][b] = (f32x4){0.f, 0.f, 0.f, 0.f};

  for (int k0 = 0; k0 < 1024; k0 += 128) {
#pragma unroll
    for (int p = 0; p < 4; ++p) {  // A: 64x128 = 1024 chunks
      int idx = p * 256 + t; int row = idx >> 4; int cs = (idx & 15) ^ (row & 7);
      glds16(Ab + (size_t)(row0 + row) * 1024 + k0 + cs * 8, &As[idx * 8]);
    }
#pragma unroll
    for (int p = 0; p < 4; ++p) {  // B: 64x128 = 1024 chunks
      int idx = p * 256 + t; int row = idx >> 4; int cs = (idx & 15) ^ (row & 7);
      glds16(Sb + (size_t)(n0 + row) * 1024 + k0 + cs * 8, &Bs[idx * 8]);
    }
    __syncthreads();
    s16x8 af[2][4], bf[2][4];
#pragma unroll
    for (int mi = 0; mi < 2; ++mi) {
      int row = wy + mi * 16 + l16;
#pragma unroll
      for (int ks = 0; ks < 4; ++ks) {
        int cl = (ks * 4 + quad) ^ (row & 7);
        af[mi][ks] = *(const s16x8*)&As[row * 128 + cl * 8];
      }
    }
#pragma unroll
    for (int ni = 0; ni < 2; ++ni) {
      int row = wx + ni * 16 + l16;
#pragma unroll
      for (int ks = 0; ks < 4; ++ks) {
        int cl = (ks * 4 + quad) ^ (row & 7);
        bf[ni][ks] = *(const s16x8*)&Bs[row * 128 + cl * 8];
      }
    }
#pragma unroll
    for (int ks = 0; ks < 4; ++ks)
#pragma unroll
      for (int mi = 0; mi < 2; ++mi)
#pragma unroll
        for (int ni = 0; ni < 2; ++ni)
          acc[mi][ni] = __builtin_amdgcn_mfma_f32_16x16x32_bf16(af[mi][ks], bf[ni][ks], acc[mi][ni], 0, 0, 0);
    __syncthreads();
  }

#pragma unroll
  for (int mi = 0; mi < 2; ++mi) {
    int frow0 = row0 + wy + mi * 16 + quad * 4;
    int b = frow0 / fdiv, c0 = frow0 - b * fdiv;
#pragma unroll
    for (int ni = 0; ni < 2; ++ni) {
      int n = n0 + wx + ni * 16 + l16;
      if (n < 1000) {
        u16 pk[4];
#pragma unroll
        for (int r = 0; r < 4; ++r) {
          float v = alpha * acc[mi][ni][r];
          if (flags & 1) v += beta * bf2f(g.Res[mode][(size_t)(frow0 + r) * 1024 + n]);
          u16 h = (u16)f2bf(v);
          pk[r] = h;
          if (flags & 2) g.Yt[mode][(size_t)(frow0 + r) * 1024 + n] = h;
        }
        u64 pv = (u64)pk[0] | ((u64)pk[1] << 16) | ((u64)pk[2] << 32) | ((u64)pk[3] << 48);
        *(u64*)&g.AgA[mode][(size_t)(n * 8 + b) * 256 + agbase + c0] = pv;
        if ((flags & 4) && c0 < 16)
          *(u64*)&g.AgX[mode][(size_t)(n * 8 + b) * 256 + agbase + c0] = pv;
      }
    }
  }
}

// ---------------------------------------------------------------------------
// meta3 (v6, proven): out[r,o] = act( sum_d ew[n,d]*(A[r,:].Btd[d*O+o,:]) + b )
// Block: 64 rows x 64 out-cols (oc = blockIdx.x). Prologue stages A THROUGH
// Bs, hoists fragments to registers (AGPR-resident); then 16 d-tiles of B
// single-buffered in Bs with __syncthreads. LDS 33.3KB -> 4 blocks/CU.
// ---------------------------------------------------------------------------
struct Meta3Args {
  const u16* Ag;        // [3][8000][256]
  const u16* Bt;        // [O*16][256] d-major
  const float* emb[3];
  const float* me;
  const float* Bias;    // [3][1000][O]
  const float* state[3];
  u16* ZSt;             // [3][512][1024]
  u16* AgU;             // [3][8000][256]
  float* Rb;            // [3][8000][64]
  float* out;
};

__global__ __launch_bounds__(256, 4) void meta3(Meta3Args A, int is_gate, int O) {
  const int mode = blockIdx.z;
  const int row0 = blockIdx.y * 64;
  const int n0 = row0 >> 3;
  const int oc = blockIdx.x;          // out-col block: gate 0/1, update 0
  const int ocbase = oc * 64;

  __shared__ u16 Bs[64 * 256];   // 32KB: A-stage in prologue, then B tiles
  __shared__ float ewS[8][17];

  const int t = threadIdx.x;
  if (t < 128) {
    int nl = t >> 4, d = t & 15;
    ewS[nl][d] = A.emb[mode][(n0 + nl) * 16 + d] * A.me[mode * 16 + d];
  }

  const int lane = t & 63, wid = t >> 6;
  const int l16 = lane & 15, quad = lane >> 4;
  const int wy = (wid >> 1) * 32, wx = (wid & 1) * 32;
  const u16* Agm = A.Ag + (size_t)mode * 2048000;

  // prologue: stage A rows [row0,row0+64) x K256 into Bs, hoist to registers
#pragma unroll
  for (int p = 0; p < 8; ++p) {
    int idx = p * 256 + t; int row = idx >> 5; int cs = (idx & 31) ^ (row & 7);
    glds16(Agm + (size_t)(row0 + row) * 256 + cs * 8, &Bs[idx * 8]);
  }
  __syncthreads();

  s16x8 afr[2][8];   // AGPR-resident (unified file); no class constraints
#pragma unroll
  for (int mi = 0; mi < 2; ++mi) {
    int row = wy + mi * 16 + l16;
#pragma unroll
    for (int ki = 0; ki < 8; ++ki) {
      int cl = (ki * 4 + quad) ^ (row & 7);
      afr[mi][ki] = *(const s16x8*)&Bs[row * 256 + cl * 8];
    }
  }
  __syncthreads();   // hoist reads retired before Bs is overwritten

  f32x4 outacc[2][2];
#pragma unroll
  for (int a = 0; a < 2; ++a)
#pragma unroll
    for (int b = 0; b < 2; ++b) outacc[a][b] = (f32x4){0.f, 0.f, 0.f, 0.f};

  for (int tl = 0; tl < 16; ++tl) {           // tl == d
    const int brow0 = tl * O + ocbase;
#pragma unroll
    for (int p = 0; p < 8; ++p) {
      int idx = p * 256 + t; int row = idx >> 5; int cs = (idx & 31) ^ (row & 7);
      glds16(A.Bt + (size_t)(brow0 + row) * 256 + cs * 8, &Bs[idx * 8]);
    }
    __syncthreads();   // B tile staged

    f32x4 acc[2][2];
#pragma unroll
    for (int a = 0; a < 2; ++a)
#pragma unroll
      for (int b = 0; b < 2; ++b) acc[a][b] = (f32x4){0.f, 0.f, 0.f, 0.f};

#pragma unroll
    for (int ki = 0; ki < 8; ++ki) {
      s16x8 bfr[2];
#pragma unroll
      for (int ni = 0; ni < 2; ++ni) {
        int row = wx + ni * 16 + l16;
        int cl = (ki * 4 + quad) ^ (row & 7);
        bfr[ni] = *(const s16x8*)&Bs[row * 256 + cl * 8];
      }
#pragma unroll
      for (int mi = 0; mi < 2; ++mi)
#pragma unroll
        for (int ni = 0; ni < 2; ++ni)
          acc[mi][ni] = __builtin_amdgcn_mfma_f32_16x16x32_bf16(afr[mi][ki], bfr[ni], acc[mi][ni], 0, 0, 0);
    }

    // fold d: outacc += ew[n,d] * acc
#pragma unroll
    for (int mi = 0; mi < 2; ++mi) {
      int nl = (wy + mi * 16 + quad * 4) >> 3;
      float s = ewS[nl][tl];
#pragma unroll
      for (int ni = 0; ni < 2; ++ni)
#pragma unroll
        for (int r = 0; r < 4; ++r)
          outacc[mi][ni][r] += s * acc[mi][ni][r];
    }
    __syncthreads();   // Bs reads retired before next tile's stage
  }

  // epilogue: bias + activation + store, straight from registers
#pragma unroll
  for (int mi = 0; mi < 2; ++mi)
#pragma unroll
    for (int ni = 0; ni < 2; ++ni)
#pragma unroll
      for (int r = 0; r < 4; ++r) {
        int row = row0 + wy + mi * 16 + quad * 4 + r;
        int n = row >> 3, b = row & 7;
        int o = ocbase + wx + ni * 16 + l16;
        float pre = outacc[mi][ni][r] + A.Bias[(size_t)mode * 1000 * O + n * O + o];
        if (is_gate) {
          float sg = 1.f / (1.f + __expf(-pre));
          if (o < 64) {
            float st = A.state[mode][(b * 1000 + n) * 64 + o];
            float zs = sg * st;
            A.ZSt[(size_t)mode * 524288 + (size_t)(b * 64 + o) * 1024 + n] = (u16)f2bf(zs);
            A.AgU[(size_t)mode * 2048000 + (size_t)row * 256 + 16 + o] = (u16)f2bf(zs);
          } else {
            A.Rb[(size_t)mode * 512000 + row * 64 + (o - 64)] = sg;
          }
        } else {
          float hc = tanhf(pre);
          float rr = A.Rb[(size_t)mode * 512000 + row * 64 + o];
          float st = A.state[mode][(b * 1000 + n) * 64 + o];
          A.out[(size_t)mode * 512000 + (b * 1000 + n) * 64 + o] = rr * st + (1.f - rr) * hc;
        }
      }
}

// ---------------------------------------------------------------------------
extern "C" void kernel_launch(void* const* d_in, const int* in_sizes, int n_in,
                              void* d_out, int out_size, void* d_ws, size_t ws_size,
                              hipStream_t stream) {
  const float* x[3]   = {(const float*)d_in[0], (const float*)d_in[1], (const float*)d_in[2]};
  const float* st[3]  = {(const float*)d_in[3], (const float*)d_in[4], (const float*)d_in[5]};
  const float* S[3]   = {(const float*)d_in[6], (const float*)d_in[7], (const float*)d_in[8]};
  const float* emb[3] = {(const float*)d_in[9], (const float*)d_in[10], (const float*)d_in[11]};
  const float* me = (const float*)d_in[12];
  const float* Wg = (const float*)d_in[13];
  const float* Bg = (const float*)d_in[14];
  const float* Wu = (const float*)d_in[15];
  const float* Bu = (const float*)d_in[16];
  float* out = (float*)d_out;

  float* BiG = (float*)d_ws;            // 3*1000*128
  float* BiU = BiG + 384000;            // 3*1000*64
  float* Rb  = BiU + 192000;            // 3*8000*64
  u16* S16 = (u16*)(Rb + 1536000);      // 3*1024*1024
  u16* Xt  = S16 + 3145728;             // 3*640*1024
  u16* T1t = Xt + 1966080;              // 3*640*1024
  u16* ZSt = T1t + 1966080;             // 3*512*1024
  u16* SZ1t= ZSt + 1572864;             // 3*512*1024
  u16* Ag  = SZ1t + 1572864;            // 3*8000*256
  u16* AgU = Ag + 6144000;              // 3*8000*256
  u16* BtG = AgU + 6144000;             // 2048*256
  u16* BtU = BtG + 524288;              // 1024*256

  {
    PrepAuxArgs P;
    for (int m = 0; m < 3; ++m) { P.x[m] = x[m]; P.st[m] = st[m]; P.S[m] = S[m]; }
    P.S16 = S16; P.Xt = Xt; P.Ag = Ag; P.AgU = AgU; P.T1t = T1t; P.ZSt = ZSt; P.SZ1t = SZ1t;
    P.e0 = emb[0]; P.e1 = emb[1]; P.e2 = emb[2]; P.me = me;
    P.Bg = Bg; P.Bu = Bu; P.Wg = Wg; P.Wu = Wu;
    P.BiG = BiG; P.BiU = BiU; P.BtG = BtG; P.BtU = BtU;
    prep_aux<<<13431, 256, 0, stream>>>(P);
  }

  // cheb1: T1t = Xt @ S^T -> T1t + Ag[80..159] (+AgU x-part)
  {
    ChebArgs2 a;
    for (int m = 0; m < 3; ++m) {
      a.S16[m] = S16 + (size_t)m * 1048576; a.A[m] = Xt + (size_t)m * 655360;
      a.Res[m] = nullptr; a.Yt[m] = T1t + (size_t)m * 655360;
      a.AgA[m] = Ag + (size_t)m * 2048000; a.AgX[m] = AgU + (size_t)m * 2048000;
    }
    cheb_v5<<<dim3(16, 10, 3), 256, 0, stream>>>(a, 80, 80, 1.f, 0.f, 2 | 4);
  }
  // cheb2: T2t = 2*T1t @ S^T - Xt -> Ag[160..239] (+AgU x-part)
  {
    ChebArgs2 a;
    for (int m = 0; m < 3; ++m) {
      a.S16[m] = S16 + (size_t)m * 1048576; a.A[m] = T1t + (size_t)m * 655360;
      a.Res[m] = Xt + (size_t)m * 655360; a.Yt[m] = nullptr;
      a.AgA[m] = Ag + (size_t)m * 2048000; a.AgX[m] = AgU + (size_t)m * 2048000;
    }
    cheb_v5<<<dim3(16, 10, 3), 256, 0, stream>>>(a, 80, 160, 2.f, -1.f, 1 | 4);
  }
  // gate meta: reads Ag; writes ZSt + AgU[16..79] + Rb  (oc split: grid.x=2)
  {
    Meta3Args a;
    a.Ag = Ag; a.Bt = BtG; a.me = me; a.Bias = BiG;
    a.ZSt = ZSt; a.AgU = AgU; a.Rb = Rb; a.out = out;
    for (int m = 0; m < 3; ++m) { a.emb[m] = emb[m]; a.state[m] = st[m]; }
    meta3<<<dim3(2, 125, 3), 256, 0, stream>>>(a, 1, 128);
  }
  // cheb3: SZ1t = ZSt @ S^T -> SZ1t + AgU[96..159]
  {
    ChebArgs2 a;
    for (int m = 0; m < 3; ++m) {
      a.S16[m] = S16 + (size_t)m * 1048576; a.A[m] = ZSt + (size_t)m * 524288;
      a.Res[m] = nullptr; a.Yt[m] = SZ1t + (size_t)m * 524288;
      a.AgA[m] = AgU + (size_t)m * 2048000; a.AgX[m] = nullptr;
    }
    cheb_v5<<<dim3(16, 8, 3), 256, 0, stream>>>(a, 64, 96, 1.f, 0.f, 2);
  }
  // cheb4: SZ2t = 2*SZ1t @ S^T - ZSt -> AgU[176..239]
  {
    ChebArgs2 a;
    for (int m = 0; m < 3; ++m) {
      a.S16[m] = S16 + (size_t)m * 1048576; a.A[m] = SZ1t + (size_t)m * 524288;
      a.Res[m] = ZSt + (size_t)m * 524288; a.Yt[m] = nullptr;
      a.AgA[m] = AgU + (size_t)m * 2048000; a.AgX[m] = nullptr;
    }
    cheb_v5<<<dim3(16, 8, 3), 256, 0, stream>>>(a, 64, 176, 2.f, -1.f, 1);
  }
  // update meta: reads AgU; writes out
  {
    Meta3Args a;
    a.Ag = AgU; a.Bt = BtU; a.me = me; a.Bias = BiU;
    a.ZSt = ZSt; a.AgU = AgU; a.Rb = Rb; a.out = out;
    for (int m = 0; m < 3; ++m) { a.emb[m] = emb[m]; a.state[m] = st[m]; }
    meta3<<<dim3(1, 125, 3), 256, 0, stream>>>(a, 0, 64);
  }
}

// Round 12
// 254.416 us; speedup vs baseline: 1.1532x; 1.0114x over previous
//
#include <hip/hip_runtime.h>
#include <math.h>

// ---------------------------------------------------------------------------
// HimNet multimode v15. B=8,N=1000,CIN=16,H=64,D=16,K=3,XIN=80,K*XIN=240,2H=128
//
// v15 = v14 + cheb f-tile 64->32 (cheb_v6):
//   cheb is latency-chain bound at 1.9 blocks/CU (grid 480/256; BW model
//   predicts ~7us vs ~30 observed). Smaller f-tile doubles the grid
//   (960 / 768 blocks) -> ~3.75 blocks/CU co-resident chains; per-block
//   chain unchanged (8 k-steps, BK=128). LDS 24KB, launch_bounds(256,4).
//   Same mechanism that works in meta3 (block-level overlap, m114).
// meta3 = proven v6 structure (52-54us). prep_aux merged (v14).
// Closed lines: meta3 pipelining (v5/v8/v9/v10/v12/v13 all failed:
// counted-vmcnt breaks locality/occupancy; afr[4][8] won't stay resident;
// "+v" pins spill; __syncthreads drains vmcnt so reg-staging can't fly).
// ---------------------------------------------------------------------------

typedef __attribute__((ext_vector_type(8))) short s16x8;
typedef __attribute__((ext_vector_type(4))) float f32x4;
typedef unsigned short u16;
typedef unsigned int u32;
typedef unsigned long long u64;

__device__ __forceinline__ u32 f2bf(float f) {
  union { float f; u32 u; } v; v.f = f;
  return (v.u + 0x7FFFu + ((v.u >> 16) & 1u)) >> 16;  // RNE
}
__device__ __forceinline__ float bf2f(u16 h) {
  union { u32 u; float f; } v; v.u = (u32)h << 16; return v.f;
}
__device__ __forceinline__ u64 pk4(float a, float b, float c, float d) {
  return (u64)f2bf(a) | ((u64)f2bf(b) << 16) | ((u64)f2bf(c) << 32) |
         ((u64)f2bf(d) << 48);
}
__device__ __forceinline__ void glds16(const u16* g, u16* l) {
  __builtin_amdgcn_global_load_lds(
      (const __attribute__((address_space(1))) void*)g,
      (__attribute__((address_space(3))) void*)l, 16, 0, 0);
}

// ---------------------------------------------------------------------------
// prep_aux: prep (4 elems/thread) + aux (1 elem/thread) in one launch (v14).
// ---------------------------------------------------------------------------
#define E0 3145728
#define E1 1966080
#define E2 1920000
#define E3 384000
#define E4 384000
#define E5 384000
#define E6 119808
// prep total = 8303616 elems = 2075904 threads; aux total = 1362432 threads
// grid = 8109 + 5322 = 13431 blocks of 256

struct PrepAuxArgs {
  const float* x[3]; const float* st[3]; const float* S[3];
  u16 *S16, *Xt, *Ag, *AgU, *T1t, *ZSt, *SZ1t;
  const float *e0, *e1, *e2, *me, *Bg, *Bu, *Wg, *Wu;
  float *BiG, *BiU; u16 *BtG, *BtU;
};

__global__ void prep_aux(PrepAuxArgs P) {
  long tid = (long)blockIdx.x * 256 + threadIdx.x;
  if (tid < 2075904) {        // ---- prep path: 4 elems ----
    long idx = tid * 4;
    if (idx < E0) {  // S16 incl pads: 4 consecutive k, same n
      int m = (int)(idx >> 20); int rem = (int)(idx & 1048575);
      int n = rem >> 10, k = rem & 1023;
      u64 pv = 0;
      if (n < 1000 && k < 1000) {
        f32x4 v = *(const f32x4*)&P.S[m][n * 1000 + k];
        pv = pk4(v[0], v[1], v[2], v[3]);
      }
      *(u64*)&P.S16[(size_t)m * 1048576 + rem] = pv; return;
    }
    idx -= E0;
    if (idx < E1) {  // Xt: 4 consecutive nn, same col
      int m = (int)(idx / 655360); int rem = (int)(idx % 655360);
      int col = rem >> 10, nn = rem & 1023;
      int b = col / 80, c = col % 80;
      u64 pv = 0;
      if (nn < 1000) {
        float f[4];
#pragma unroll
        for (int j = 0; j < 4; ++j)
          f[j] = (c < 16) ? P.x[m][(b * 1000 + nn + j) * 16 + c]
                          : P.st[m][(b * 1000 + nn + j) * 64 + c - 16];
        pv = pk4(f[0], f[1], f[2], f[3]);
      }
      *(u64*)&P.Xt[(size_t)m * 655360 + rem] = pv; return;
    }
    idx -= E1;
    if (idx < E2) {  // Ag kc0: 4 consecutive c, same r
      int m = (int)(idx / 640000); int rem = (int)(idx % 640000);
      int r = rem / 80, c = rem % 80;
      int n = r >> 3, b = r & 7;
      f32x4 v = (c < 16) ? *(const f32x4*)&P.x[m][(b * 1000 + n) * 16 + c]
                         : *(const f32x4*)&P.st[m][(b * 1000 + n) * 64 + c - 16];
      *(u64*)&P.Ag[(size_t)m * 2048000 + (size_t)r * 256 + c] =
          pk4(v[0], v[1], v[2], v[3]);
      return;
    }
    idx -= E2;
    if (idx < E3) {  // Ag K-pad 240..255
      int m = (int)(idx / 128000); int rem = (int)(idx % 128000);
      int r = rem / 16, c = 240 + rem % 16;
      *(u64*)&P.Ag[(size_t)m * 2048000 + (size_t)r * 256 + c] = 0; return;
    }
    idx -= E3;
    if (idx < E4) {  // AgU kc0 x-part (cols 0..15)
      int m = (int)(idx / 128000); int rem = (int)(idx % 128000);
      int r = rem / 16, c = rem % 16;
      int n = r >> 3, b = r & 7;
      f32x4 v = *(const f32x4*)&P.x[m][(b * 1000 + n) * 16 + c];
      *(u64*)&P.AgU[(size_t)m * 2048000 + (size_t)r * 256 + c] =
          pk4(v[0], v[1], v[2], v[3]);
      return;
    }
    idx -= E4;
    if (idx < E5) {  // AgU K-pad
      int m = (int)(idx / 128000); int rem = (int)(idx % 128000);
      int r = rem / 16, c = 240 + rem % 16;
      *(u64*)&P.AgU[(size_t)m * 2048000 + (size_t)r * 256 + c] = 0; return;
    }
    idx -= E5;
    if (idx < E6) {  // n-pad rows (k=1000..1023) of T1t/ZSt/SZ1t
      int m = (int)(idx / 39936); int rem = (int)(idx % 39936);
      if (rem < 15360) { int col = rem / 24, j = rem % 24;
        *(u64*)&P.T1t[(size_t)m * 655360 + col * 1024 + 1000 + j] = 0; }
      else if (rem < 27648) { int e = rem - 15360; int col = e / 24, j = e % 24;
        *(u64*)&P.ZSt[(size_t)m * 524288 + col * 1024 + 1000 + j] = 0; }
      else { int e = rem - 27648; int col = e / 24, j = e % 24;
        *(u64*)&P.SZ1t[(size_t)m * 524288 + col * 1024 + 1000 + j] = 0; }
      return;
    }
    return;
  }
  // ---- aux path: 1 elem ----
  int idx = (int)(tid - 2075904);
  if (idx < 384000) {        // BiG[mode][n*128+o]
    int mode = idx / 128000, rem = idx % 128000;
    int n = rem >> 7, o = rem & 127;
    const float* emb = (mode == 0) ? P.e0 : (mode == 1) ? P.e1 : P.e2;
    float s = 0.f;
#pragma unroll
    for (int d = 0; d < 16; ++d)
      s += emb[n * 16 + d] * P.me[mode * 16 + d] * P.Bg[d * 128 + o];
    P.BiG[idx] = s; return;
  }
  idx -= 384000;
  if (idx < 192000) {        // BiU[mode][n*64+o]
    int mode = idx / 64000, rem = idx % 64000;
    int n = rem >> 6, o = rem & 63;
    const float* emb = (mode == 0) ? P.e0 : (mode == 1) ? P.e1 : P.e2;
    float s = 0.f;
#pragma unroll
    for (int d = 0; d < 16; ++d)
      s += emb[n * 16 + d] * P.me[mode * 16 + d] * P.Bu[d * 64 + o];
    P.BiU[idx] = s; return;
  }
  idx -= 192000;
  if (idx < 524288) {        // BtG d-major: [(d*128+o)][k]
    int col = idx >> 8, k = idx & 255;
    int d = col >> 7, o = col & 127;
    P.BtG[idx] = (k < 240) ? (u16)f2bf(P.Wg[d * 30720 + k * 128 + o]) : (u16)0;
    return;
  }
  idx -= 524288;
  if (idx < 262144) {        // BtU d-major: [(d*64+o)][k]
    int col = idx >> 8, k = idx & 255;
    int d = col >> 6, o = col & 63;
    P.BtU[idx] = (k < 240) ? (u16)f2bf(P.Wu[d * 15360 + k * 64 + o]) : (u16)0;
  }
}

// ---------------------------------------------------------------------------
// cheb_v6: D[f][n] = alpha*sum_k A[f][k]*S16[n][k] (+beta*Res[f][n])
// Tile 32(f) x 64(n), BK=128, 8 barriered k-steps. 4 waves column-split:
// wave w covers cols [w*16, w*16+16). LDS 24KB -> 4+ blocks/CU; grid
// doubles vs v5 (960 / 768 blocks) for chain-level latency overlap.
// flags: 1=hasRes, 2=hasY, 4=hasAgX
// ---------------------------------------------------------------------------
struct ChebArgs2 {
  const u16* S16[3]; const u16* A[3]; const u16* Res[3];
  u16* Yt[3]; u16* AgA[3]; u16* AgX[3];
};

__global__ __launch_bounds__(256, 4) void cheb_v6(ChebArgs2 g, int fdiv, int agbase,
                                                  float alpha, float beta, int flags) {
  const int mode = blockIdx.z;
  const u16* __restrict__ Ab = g.A[mode];
  const u16* __restrict__ Sb = g.S16[mode];

  __shared__ u16 As[32 * 128];   // 8KB
  __shared__ u16 Bs[64 * 128];   // 16KB

  const int t = threadIdx.x;
  const int row0 = blockIdx.y * 32, n0 = blockIdx.x * 64;
  const int lane = t & 63, wid = t >> 6;
  const int l16 = lane & 15, quad = lane >> 4;
  const int wx = wid * 16;       // wave's 16-col group

  f32x4 acc[2];
#pragma unroll
  for (int a = 0; a < 2; ++a) acc[a] = (f32x4){0.f, 0.f, 0.f, 0.f};

  for (int k0 = 0; k0 < 1024; k0 += 128) {
#pragma unroll
    for (int p = 0; p < 2; ++p) {  // A: 32x128 = 512 chunks
      int idx = p * 256 + t; int row = idx >> 4; int cs = (idx & 15) ^ (row & 7);
      glds16(Ab + (size_t)(row0 + row) * 1024 + k0 + cs * 8, &As[idx * 8]);
    }
#pragma unroll
    for (int p = 0; p < 4; ++p) {  // B: 64x128 = 1024 chunks
      int idx = p * 256 + t; int row = idx >> 4; int cs = (idx & 15) ^ (row & 7);
      glds16(Sb + (size_t)(n0 + row) * 1024 + k0 + cs * 8, &Bs[idx * 8]);
    }
    __syncthreads();
    s16x8 af[2][4], bf[4];
#pragma unroll
    for (int mi = 0; mi < 2; ++mi) {
      int row = mi * 16 + l16;
#pragma unroll
      for (int ks = 0; ks < 4; ++ks) {
        int cl = (ks * 4 + quad) ^ (row & 7);
        af[mi][ks] = *(const s16x8*)&As[row * 128 + cl * 8];
      }
    }
    {
      int row = wx + l16;
#pragma unroll
      for (int ks = 0; ks < 4; ++ks) {
        int cl = (ks * 4 + quad) ^ (row & 7);
        bf[ks] = *(const s16x8*)&Bs[row * 128 + cl * 8];
      }
    }
#pragma unroll
    for (int ks = 0; ks < 4; ++ks)
#pragma unroll
      for (int mi = 0; mi < 2; ++mi)
        acc[mi] = __builtin_amdgcn_mfma_f32_16x16x32_bf16(af[mi][ks], bf[ks], acc[mi], 0, 0, 0);
    __syncthreads();
  }

#pragma unroll
  for (int mi = 0; mi < 2; ++mi) {
    int frow0 = row0 + mi * 16 + quad * 4;
    int b = frow0 / fdiv, c0 = frow0 - b * fdiv;
    int n = n0 + wx + l16;
    if (n < 1000) {
      u16 pk[4];
#pragma unroll
      for (int r = 0; r < 4; ++r) {
        float v = alpha * acc[mi][r];
        if (flags & 1) v += beta * bf2f(g.Res[mode][(size_t)(frow0 + r) * 1024 + n]);
        u16 h = (u16)f2bf(v);
        pk[r] = h;
        if (flags & 2) g.Yt[mode][(size_t)(frow0 + r) * 1024 + n] = h;
      }
      u64 pv = (u64)pk[0] | ((u64)pk[1] << 16) | ((u64)pk[2] << 32) | ((u64)pk[3] << 48);
      *(u64*)&g.AgA[mode][(size_t)(n * 8 + b) * 256 + agbase + c0] = pv;
      if ((flags & 4) && c0 < 16)
        *(u64*)&g.AgX[mode][(size_t)(n * 8 + b) * 256 + agbase + c0] = pv;
    }
  }
}

// ---------------------------------------------------------------------------
// meta3 (v6, proven): out[r,o] = act( sum_d ew[n,d]*(A[r,:].Btd[d*O+o,:]) + b )
// Block: 64 rows x 64 out-cols (oc = blockIdx.x). Prologue stages A THROUGH
// Bs, hoists fragments to registers (AGPR-resident); then 16 d-tiles of B
// single-buffered in Bs with __syncthreads. LDS 33.3KB -> 4 blocks/CU.
// ---------------------------------------------------------------------------
struct Meta3Args {
  const u16* Ag;        // [3][8000][256]
  const u16* Bt;        // [O*16][256] d-major
  const float* emb[3];
  const float* me;
  const float* Bias;    // [3][1000][O]
  const float* state[3];
  u16* ZSt;             // [3][512][1024]
  u16* AgU;             // [3][8000][256]
  float* Rb;            // [3][8000][64]
  float* out;
};

__global__ __launch_bounds__(256, 4) void meta3(Meta3Args A, int is_gate, int O) {
  const int mode = blockIdx.z;
  const int row0 = blockIdx.y * 64;
  const int n0 = row0 >> 3;
  const int oc = blockIdx.x;          // out-col block: gate 0/1, update 0
  const int ocbase = oc * 64;

  __shared__ u16 Bs[64 * 256];   // 32KB: A-stage in prologue, then B tiles
  __shared__ float ewS[8][17];

  const int t = threadIdx.x;
  if (t < 128) {
    int nl = t >> 4, d = t & 15;
    ewS[nl][d] = A.emb[mode][(n0 + nl) * 16 + d] * A.me[mode * 16 + d];
  }

  const int lane = t & 63, wid = t >> 6;
  const int l16 = lane & 15, quad = lane >> 4;
  const int wy = (wid >> 1) * 32, wx = (wid & 1) * 32;
  const u16* Agm = A.Ag + (size_t)mode * 2048000;

  // prologue: stage A rows [row0,row0+64) x K256 into Bs, hoist to registers
#pragma unroll
  for (int p = 0; p < 8; ++p) {
    int idx = p * 256 + t; int row = idx >> 5; int cs = (idx & 31) ^ (row & 7);
    glds16(Agm + (size_t)(row0 + row) * 256 + cs * 8, &Bs[idx * 8]);
  }
  __syncthreads();

  s16x8 afr[2][8];   // AGPR-resident (unified file); no class constraints
#pragma unroll
  for (int mi = 0; mi < 2; ++mi) {
    int row = wy + mi * 16 + l16;
#pragma unroll
    for (int ki = 0; ki < 8; ++ki) {
      int cl = (ki * 4 + quad) ^ (row & 7);
      afr[mi][ki] = *(const s16x8*)&Bs[row * 256 + cl * 8];
    }
  }
  __syncthreads();   // hoist reads retired before Bs is overwritten

  f32x4 outacc[2][2];
#pragma unroll
  for (int a = 0; a < 2; ++a)
#pragma unroll
    for (int b = 0; b < 2; ++b) outacc[a][b] = (f32x4){0.f, 0.f, 0.f, 0.f};

  for (int tl = 0; tl < 16; ++tl) {           // tl == d
    const int brow0 = tl * O + ocbase;
#pragma unroll
    for (int p = 0; p < 8; ++p) {
      int idx = p * 256 + t; int row = idx >> 5; int cs = (idx & 31) ^ (row & 7);
      glds16(A.Bt + (size_t)(brow0 + row) * 256 + cs * 8, &Bs[idx * 8]);
    }
    __syncthreads();   // B tile staged

    f32x4 acc[2][2];
#pragma unroll
    for (int a = 0; a < 2; ++a)
#pragma unroll
      for (int b = 0; b < 2; ++b) acc[a][b] = (f32x4){0.f, 0.f, 0.f, 0.f};

#pragma unroll
    for (int ki = 0; ki < 8; ++ki) {
      s16x8 bfr[2];
#pragma unroll
      for (int ni = 0; ni < 2; ++ni) {
        int row = wx + ni * 16 + l16;
        int cl = (ki * 4 + quad) ^ (row & 7);
        bfr[ni] = *(const s16x8*)&Bs[row * 256 + cl * 8];
      }
#pragma unroll
      for (int mi = 0; mi < 2; ++mi)
#pragma unroll
        for (int ni = 0; ni < 2; ++ni)
          acc[mi][ni] = __builtin_amdgcn_mfma_f32_16x16x32_bf16(afr[mi][ki], bfr[ni], acc[mi][ni], 0, 0, 0);
    }

    // fold d: outacc += ew[n,d] * acc
#pragma unroll
    for (int mi = 0; mi < 2; ++mi) {
      int nl = (wy + mi * 16 + quad * 4) >> 3;
      float s = ewS[nl][tl];
#pragma unroll
      for (int ni = 0; ni < 2; ++ni)
#pragma unroll
        for (int r = 0; r < 4; ++r)
          outacc[mi][ni][r] += s * acc[mi][ni][r];
    }
    __syncthreads();   // Bs reads retired before next tile's stage
  }

  // epilogue: bias + activation + store, straight from registers
#pragma unroll
  for (int mi = 0; mi < 2; ++mi)
#pragma unroll
    for (int ni = 0; ni < 2; ++ni)
#pragma unroll
      for (int r = 0; r < 4; ++r) {
        int row = row0 + wy + mi * 16 + quad * 4 + r;
        int n = row >> 3, b = row & 7;
        int o = ocbase + wx + ni * 16 + l16;
        float pre = outacc[mi][ni][r] + A.Bias[(size_t)mode * 1000 * O + n * O + o];
        if (is_gate) {
          float sg = 1.f / (1.f + __expf(-pre));
          if (o < 64) {
            float st = A.state[mode][(b * 1000 + n) * 64 + o];
            float zs = sg * st;
            A.ZSt[(size_t)mode * 524288 + (size_t)(b * 64 + o) * 1024 + n] = (u16)f2bf(zs);
            A.AgU[(size_t)mode * 2048000 + (size_t)row * 256 + 16 + o] = (u16)f2bf(zs);
          } else {
            A.Rb[(size_t)mode * 512000 + row * 64 + (o - 64)] = sg;
          }
        } else {
          float hc = tanhf(pre);
          float rr = A.Rb[(size_t)mode * 512000 + row * 64 + o];
          float st = A.state[mode][(b * 1000 + n) * 64 + o];
          A.out[(size_t)mode * 512000 + (b * 1000 + n) * 64 + o] = rr * st + (1.f - rr) * hc;
        }
      }
}

// ---------------------------------------------------------------------------
extern "C" void kernel_launch(void* const* d_in, const int* in_sizes, int n_in,
                              void* d_out, int out_size, void* d_ws, size_t ws_size,
                              hipStream_t stream) {
  const float* x[3]   = {(const float*)d_in[0], (const float*)d_in[1], (const float*)d_in[2]};
  const float* st[3]  = {(const float*)d_in[3], (const float*)d_in[4], (const float*)d_in[5]};
  const float* S[3]   = {(const float*)d_in[6], (const float*)d_in[7], (const float*)d_in[8]};
  const float* emb[3] = {(const float*)d_in[9], (const float*)d_in[10], (const float*)d_in[11]};
  const float* me = (const float*)d_in[12];
  const float* Wg = (const float*)d_in[13];
  const float* Bg = (const float*)d_in[14];
  const float* Wu = (const float*)d_in[15];
  const float* Bu = (const float*)d_in[16];
  float* out = (float*)d_out;

  float* BiG = (float*)d_ws;            // 3*1000*128
  float* BiU = BiG + 384000;            // 3*1000*64
  float* Rb  = BiU + 192000;            // 3*8000*64
  u16* S16 = (u16*)(Rb + 1536000);      // 3*1024*1024
  u16* Xt  = S16 + 3145728;             // 3*640*1024
  u16* T1t = Xt + 1966080;              // 3*640*1024
  u16* ZSt = T1t + 1966080;             // 3*512*1024
  u16* SZ1t= ZSt + 1572864;             // 3*512*1024
  u16* Ag  = SZ1t + 1572864;            // 3*8000*256
  u16* AgU = Ag + 6144000;              // 3*8000*256
  u16* BtG = AgU + 6144000;             // 2048*256
  u16* BtU = BtG + 524288;              // 1024*256

  {
    PrepAuxArgs P;
    for (int m = 0; m < 3; ++m) { P.x[m] = x[m]; P.st[m] = st[m]; P.S[m] = S[m]; }
    P.S16 = S16; P.Xt = Xt; P.Ag = Ag; P.AgU = AgU; P.T1t = T1t; P.ZSt = ZSt; P.SZ1t = SZ1t;
    P.e0 = emb[0]; P.e1 = emb[1]; P.e2 = emb[2]; P.me = me;
    P.Bg = Bg; P.Bu = Bu; P.Wg = Wg; P.Wu = Wu;
    P.BiG = BiG; P.BiU = BiU; P.BtG = BtG; P.BtU = BtU;
    prep_aux<<<13431, 256, 0, stream>>>(P);
  }

  // cheb1: T1t = Xt @ S^T -> T1t + Ag[80..159] (+AgU x-part)
  {
    ChebArgs2 a;
    for (int m = 0; m < 3; ++m) {
      a.S16[m] = S16 + (size_t)m * 1048576; a.A[m] = Xt + (size_t)m * 655360;
      a.Res[m] = nullptr; a.Yt[m] = T1t + (size_t)m * 655360;
      a.AgA[m] = Ag + (size_t)m * 2048000; a.AgX[m] = AgU + (size_t)m * 2048000;
    }
    cheb_v6<<<dim3(16, 20, 3), 256, 0, stream>>>(a, 80, 80, 1.f, 0.f, 2 | 4);
  }
  // cheb2: T2t = 2*T1t @ S^T - Xt -> Ag[160..239] (+AgU x-part)
  {
    ChebArgs2 a;
    for (int m = 0; m < 3; ++m) {
      a.S16[m] = S16 + (size_t)m * 1048576; a.A[m] = T1t + (size_t)m * 655360;
      a.Res[m] = Xt + (size_t)m * 655360; a.Yt[m] = nullptr;
      a.AgA[m] = Ag + (size_t)m * 2048000; a.AgX[m] = AgU + (size_t)m * 2048000;
    }
    cheb_v6<<<dim3(16, 20, 3), 256, 0, stream>>>(a, 80, 160, 2.f, -1.f, 1 | 4);
  }
  // gate meta: reads Ag; writes ZSt + AgU[16..79] + Rb  (oc split: grid.x=2)
  {
    Meta3Args a;
    a.Ag = Ag; a.Bt = BtG; a.me = me; a.Bias = BiG;
    a.ZSt = ZSt; a.AgU = AgU; a.Rb = Rb; a.out = out;
    for (int m = 0; m < 3; ++m) { a.emb[m] = emb[m]; a.state[m] = st[m]; }
    meta3<<<dim3(2, 125, 3), 256, 0, stream>>>(a, 1, 128);
  }
  // cheb3: SZ1t = ZSt @ S^T -> SZ1t + AgU[96..159]
  {
    ChebArgs2 a;
    for (int m = 0; m < 3; ++m) {
      a.S16[m] = S16 + (size_t)m * 1048576; a.A[m] = ZSt + (size_t)m * 524288;
      a.Res[m] = nullptr; a.Yt[m] = SZ1t + (size_t)m * 524288;
      a.AgA[m] = AgU + (size_t)m * 2048000; a.AgX[m] = nullptr;
    }
    cheb_v6<<<dim3(16, 16, 3), 256, 0, stream>>>(a, 64, 96, 1.f, 0.f, 2);
  }
  // cheb4: SZ2t = 2*SZ1t @ S^T - ZSt -> AgU[176..239]
  {
    ChebArgs2 a;
    for (int m = 0; m < 3; ++m) {
      a.S16[m] = S16 + (size_t)m * 1048576; a.A[m] = SZ1t + (size_t)m * 524288;
      a.Res[m] = ZSt + (size_t)m * 524288; a.Yt[m] = nullptr;
      a.AgA[m] = AgU + (size_t)m * 2048000; a.AgX[m] = nullptr;
    }
    cheb_v6<<<dim3(16, 16, 3), 256, 0, stream>>>(a, 64, 176, 2.f, -1.f, 1);
  }
  // update meta: reads AgU; writes out
  {
    Meta3Args a;
    a.Ag = AgU; a.Bt = BtU; a.me = me; a.Bias = BiU;
    a.ZSt = ZSt; a.AgU = AgU; a.Rb = Rb; a.out = out;
    for (int m = 0; m < 3; ++m) { a.emb[m] = emb[m]; a.state[m] = st[m]; }
    meta3<<<dim3(1, 125, 3), 256, 0, stream>>>(a, 0, 64);
  }
}

// Round 13
// 249.535 us; speedup vs baseline: 1.1758x; 1.0196x over previous
//
#include <hip/hip_runtime.h>
#include <math.h>

// ---------------------------------------------------------------------------
// HimNet multimode v16. B=8,N=1000,CIN=16,H=64,D=16,K=3,XIN=80,K*XIN=240,2H=128
//
// v16 = v15 + split-d update meta (meta3u):
//   meta3 is per-block chain-bound (16 d-tiles x ~3.3us; gate==update==52us
//   despite 2x work => spare CU capacity). Split the update's d-loop across
//   2 blocks (8-tile chains), write f32 partials (deterministic, no atomics)
//   into the Ag region (12.29MB, dead after gate-meta reads it), then a
//   small epilogue kernel sums halves + bias, applies tanh + GRU blend.
// Gate meta3 unchanged (no free 24.6MB for its partials; ws overflow risk).
// cheb_v6 (32x64, BK=128), prep_aux merged (v14/v15).
// Closed lines: meta3 intra-block pipelining (v5/v8/v9/v10/v12/v13).
// ---------------------------------------------------------------------------

typedef __attribute__((ext_vector_type(8))) short s16x8;
typedef __attribute__((ext_vector_type(4))) float f32x4;
typedef unsigned short u16;
typedef unsigned int u32;
typedef unsigned long long u64;

__device__ __forceinline__ u32 f2bf(float f) {
  union { float f; u32 u; } v; v.f = f;
  return (v.u + 0x7FFFu + ((v.u >> 16) & 1u)) >> 16;  // RNE
}
__device__ __forceinline__ float bf2f(u16 h) {
  union { u32 u; float f; } v; v.u = (u32)h << 16; return v.f;
}
__device__ __forceinline__ u64 pk4(float a, float b, float c, float d) {
  return (u64)f2bf(a) | ((u64)f2bf(b) << 16) | ((u64)f2bf(c) << 32) |
         ((u64)f2bf(d) << 48);
}
__device__ __forceinline__ void glds16(const u16* g, u16* l) {
  __builtin_amdgcn_global_load_lds(
      (const __attribute__((address_space(1))) void*)g,
      (__attribute__((address_space(3))) void*)l, 16, 0, 0);
}

// ---------------------------------------------------------------------------
// prep_aux: prep (4 elems/thread) + aux (1 elem/thread) in one launch.
// ---------------------------------------------------------------------------
#define E0 3145728
#define E1 1966080
#define E2 1920000
#define E3 384000
#define E4 384000
#define E5 384000
#define E6 119808
// prep total = 8303616 elems = 2075904 threads; aux total = 1362432 threads
// grid = 8109 + 5322 = 13431 blocks of 256

struct PrepAuxArgs {
  const float* x[3]; const float* st[3]; const float* S[3];
  u16 *S16, *Xt, *Ag, *AgU, *T1t, *ZSt, *SZ1t;
  const float *e0, *e1, *e2, *me, *Bg, *Bu, *Wg, *Wu;
  float *BiG, *BiU; u16 *BtG, *BtU;
};

__global__ void prep_aux(PrepAuxArgs P) {
  long tid = (long)blockIdx.x * 256 + threadIdx.x;
  if (tid < 2075904) {        // ---- prep path: 4 elems ----
    long idx = tid * 4;
    if (idx < E0) {  // S16 incl pads: 4 consecutive k, same n
      int m = (int)(idx >> 20); int rem = (int)(idx & 1048575);
      int n = rem >> 10, k = rem & 1023;
      u64 pv = 0;
      if (n < 1000 && k < 1000) {
        f32x4 v = *(const f32x4*)&P.S[m][n * 1000 + k];
        pv = pk4(v[0], v[1], v[2], v[3]);
      }
      *(u64*)&P.S16[(size_t)m * 1048576 + rem] = pv; return;
    }
    idx -= E0;
    if (idx < E1) {  // Xt: 4 consecutive nn, same col
      int m = (int)(idx / 655360); int rem = (int)(idx % 655360);
      int col = rem >> 10, nn = rem & 1023;
      int b = col / 80, c = col % 80;
      u64 pv = 0;
      if (nn < 1000) {
        float f[4];
#pragma unroll
        for (int j = 0; j < 4; ++j)
          f[j] = (c < 16) ? P.x[m][(b * 1000 + nn + j) * 16 + c]
                          : P.st[m][(b * 1000 + nn + j) * 64 + c - 16];
        pv = pk4(f[0], f[1], f[2], f[3]);
      }
      *(u64*)&P.Xt[(size_t)m * 655360 + rem] = pv; return;
    }
    idx -= E1;
    if (idx < E2) {  // Ag kc0: 4 consecutive c, same r
      int m = (int)(idx / 640000); int rem = (int)(idx % 640000);
      int r = rem / 80, c = rem % 80;
      int n = r >> 3, b = r & 7;
      f32x4 v = (c < 16) ? *(const f32x4*)&P.x[m][(b * 1000 + n) * 16 + c]
                         : *(const f32x4*)&P.st[m][(b * 1000 + n) * 64 + c - 16];
      *(u64*)&P.Ag[(size_t)m * 2048000 + (size_t)r * 256 + c] =
          pk4(v[0], v[1], v[2], v[3]);
      return;
    }
    idx -= E2;
    if (idx < E3) {  // Ag K-pad 240..255
      int m = (int)(idx / 128000); int rem = (int)(idx % 128000);
      int r = rem / 16, c = 240 + rem % 16;
      *(u64*)&P.Ag[(size_t)m * 2048000 + (size_t)r * 256 + c] = 0; return;
    }
    idx -= E3;
    if (idx < E4) {  // AgU kc0 x-part (cols 0..15)
      int m = (int)(idx / 128000); int rem = (int)(idx % 128000);
      int r = rem / 16, c = rem % 16;
      int n = r >> 3, b = r & 7;
      f32x4 v = *(const f32x4*)&P.x[m][(b * 1000 + n) * 16 + c];
      *(u64*)&P.AgU[(size_t)m * 2048000 + (size_t)r * 256 + c] =
          pk4(v[0], v[1], v[2], v[3]);
      return;
    }
    idx -= E4;
    if (idx < E5) {  // AgU K-pad
      int m = (int)(idx / 128000); int rem = (int)(idx % 128000);
      int r = rem / 16, c = 240 + rem % 16;
      *(u64*)&P.AgU[(size_t)m * 2048000 + (size_t)r * 256 + c] = 0; return;
    }
    idx -= E5;
    if (idx < E6) {  // n-pad rows (k=1000..1023) of T1t/ZSt/SZ1t
      int m = (int)(idx / 39936); int rem = (int)(idx % 39936);
      if (rem < 15360) { int col = rem / 24, j = rem % 24;
        *(u64*)&P.T1t[(size_t)m * 655360 + col * 1024 + 1000 + j] = 0; }
      else if (rem < 27648) { int e = rem - 15360; int col = e / 24, j = e % 24;
        *(u64*)&P.ZSt[(size_t)m * 524288 + col * 1024 + 1000 + j] = 0; }
      else { int e = rem - 27648; int col = e / 24, j = e % 24;
        *(u64*)&P.SZ1t[(size_t)m * 524288 + col * 1024 + 1000 + j] = 0; }
      return;
    }
    return;
  }
  // ---- aux path: 1 elem ----
  int idx = (int)(tid - 2075904);
  if (idx < 384000) {        // BiG[mode][n*128+o]
    int mode = idx / 128000, rem = idx % 128000;
    int n = rem >> 7, o = rem & 127;
    const float* emb = (mode == 0) ? P.e0 : (mode == 1) ? P.e1 : P.e2;
    float s = 0.f;
#pragma unroll
    for (int d = 0; d < 16; ++d)
      s += emb[n * 16 + d] * P.me[mode * 16 + d] * P.Bg[d * 128 + o];
    P.BiG[idx] = s; return;
  }
  idx -= 384000;
  if (idx < 192000) {        // BiU[mode][n*64+o]
    int mode = idx / 64000, rem = idx % 64000;
    int n = rem >> 6, o = rem & 63;
    const float* emb = (mode == 0) ? P.e0 : (mode == 1) ? P.e1 : P.e2;
    float s = 0.f;
#pragma unroll
    for (int d = 0; d < 16; ++d)
      s += emb[n * 16 + d] * P.me[mode * 16 + d] * P.Bu[d * 64 + o];
    P.BiU[idx] = s; return;
  }
  idx -= 192000;
  if (idx < 524288) {        // BtG d-major: [(d*128+o)][k]
    int col = idx >> 8, k = idx & 255;
    int d = col >> 7, o = col & 127;
    P.BtG[idx] = (k < 240) ? (u16)f2bf(P.Wg[d * 30720 + k * 128 + o]) : (u16)0;
    return;
  }
  idx -= 524288;
  if (idx < 262144) {        // BtU d-major: [(d*64+o)][k]
    int col = idx >> 8, k = idx & 255;
    int d = col >> 6, o = col & 63;
    P.BtU[idx] = (k < 240) ? (u16)f2bf(P.Wu[d * 15360 + k * 64 + o]) : (u16)0;
  }
}

// ---------------------------------------------------------------------------
// cheb_v6: D[f][n] = alpha*sum_k A[f][k]*S16[n][k] (+beta*Res[f][n])
// Tile 32(f) x 64(n), BK=128, 8 barriered k-steps, 4 waves column-split.
// flags: 1=hasRes, 2=hasY, 4=hasAgX
// ---------------------------------------------------------------------------
struct ChebArgs2 {
  const u16* S16[3]; const u16* A[3]; const u16* Res[3];
  u16* Yt[3]; u16* AgA[3]; u16* AgX[3];
};

__global__ __launch_bounds__(256, 4) void cheb_v6(ChebArgs2 g, int fdiv, int agbase,
                                                  float alpha, float beta, int flags) {
  const int mode = blockIdx.z;
  const u16* __restrict__ Ab = g.A[mode];
  const u16* __restrict__ Sb = g.S16[mode];

  __shared__ u16 As[32 * 128];   // 8KB
  __shared__ u16 Bs[64 * 128];   // 16KB

  const int t = threadIdx.x;
  const int row0 = blockIdx.y * 32, n0 = blockIdx.x * 64;
  const int lane = t & 63, wid = t >> 6;
  const int l16 = lane & 15, quad = lane >> 4;
  const int wx = wid * 16;       // wave's 16-col group

  f32x4 acc[2];
#pragma unroll
  for (int a = 0; a < 2; ++a) acc[a] = (f32x4){0.f, 0.f, 0.f, 0.f};

  for (int k0 = 0; k0 < 1024; k0 += 128) {
#pragma unroll
    for (int p = 0; p < 2; ++p) {  // A: 32x128 = 512 chunks
      int idx = p * 256 + t; int row = idx >> 4; int cs = (idx & 15) ^ (row & 7);
      glds16(Ab + (size_t)(row0 + row) * 1024 + k0 + cs * 8, &As[idx * 8]);
    }
#pragma unroll
    for (int p = 0; p < 4; ++p) {  // B: 64x128 = 1024 chunks
      int idx = p * 256 + t; int row = idx >> 4; int cs = (idx & 15) ^ (row & 7);
      glds16(Sb + (size_t)(n0 + row) * 1024 + k0 + cs * 8, &Bs[idx * 8]);
    }
    __syncthreads();
    s16x8 af[2][4], bf[4];
#pragma unroll
    for (int mi = 0; mi < 2; ++mi) {
      int row = mi * 16 + l16;
#pragma unroll
      for (int ks = 0; ks < 4; ++ks) {
        int cl = (ks * 4 + quad) ^ (row & 7);
        af[mi][ks] = *(const s16x8*)&As[row * 128 + cl * 8];
      }
    }
    {
      int row = wx + l16;
#pragma unroll
      for (int ks = 0; ks < 4; ++ks) {
        int cl = (ks * 4 + quad) ^ (row & 7);
        bf[ks] = *(const s16x8*)&Bs[row * 128 + cl * 8];
      }
    }
#pragma unroll
    for (int ks = 0; ks < 4; ++ks)
#pragma unroll
      for (int mi = 0; mi < 2; ++mi)
        acc[mi] = __builtin_amdgcn_mfma_f32_16x16x32_bf16(af[mi][ks], bf[ks], acc[mi], 0, 0, 0);
    __syncthreads();
  }

#pragma unroll
  for (int mi = 0; mi < 2; ++mi) {
    int frow0 = row0 + mi * 16 + quad * 4;
    int b = frow0 / fdiv, c0 = frow0 - b * fdiv;
    int n = n0 + wx + l16;
    if (n < 1000) {
      u16 pk[4];
#pragma unroll
      for (int r = 0; r < 4; ++r) {
        float v = alpha * acc[mi][r];
        if (flags & 1) v += beta * bf2f(g.Res[mode][(size_t)(frow0 + r) * 1024 + n]);
        u16 h = (u16)f2bf(v);
        pk[r] = h;
        if (flags & 2) g.Yt[mode][(size_t)(frow0 + r) * 1024 + n] = h;
      }
      u64 pv = (u64)pk[0] | ((u64)pk[1] << 16) | ((u64)pk[2] << 32) | ((u64)pk[3] << 48);
      *(u64*)&g.AgA[mode][(size_t)(n * 8 + b) * 256 + agbase + c0] = pv;
      if ((flags & 4) && c0 < 16)
        *(u64*)&g.AgX[mode][(size_t)(n * 8 + b) * 256 + agbase + c0] = pv;
    }
  }
}

// ---------------------------------------------------------------------------
// meta3 (gate, proven v6 structure): 16 d-tiles, single-buffer, 4 blocks/CU.
// ---------------------------------------------------------------------------
struct Meta3Args {
  const u16* Ag;        // [3][8000][256]
  const u16* Bt;        // [O*16][256] d-major
  const float* emb[3];
  const float* me;
  const float* Bias;    // [3][1000][O]
  const float* state[3];
  u16* ZSt;             // [3][512][1024]
  u16* AgU;             // [3][8000][256]
  float* Rb;            // [3][8000][64]
  float* out;
};

__global__ __launch_bounds__(256, 4) void meta3(Meta3Args A, int is_gate, int O) {
  const int mode = blockIdx.z;
  const int row0 = blockIdx.y * 64;
  const int n0 = row0 >> 3;
  const int oc = blockIdx.x;          // out-col block: gate 0/1
  const int ocbase = oc * 64;

  __shared__ u16 Bs[64 * 256];   // 32KB: A-stage in prologue, then B tiles
  __shared__ float ewS[8][17];

  const int t = threadIdx.x;
  if (t < 128) {
    int nl = t >> 4, d = t & 15;
    ewS[nl][d] = A.emb[mode][(n0 + nl) * 16 + d] * A.me[mode * 16 + d];
  }

  const int lane = t & 63, wid = t >> 6;
  const int l16 = lane & 15, quad = lane >> 4;
  const int wy = (wid >> 1) * 32, wx = (wid & 1) * 32;
  const u16* Agm = A.Ag + (size_t)mode * 2048000;

  // prologue: stage A rows [row0,row0+64) x K256 into Bs, hoist to registers
#pragma unroll
  for (int p = 0; p < 8; ++p) {
    int idx = p * 256 + t; int row = idx >> 5; int cs = (idx & 31) ^ (row & 7);
    glds16(Agm + (size_t)(row0 + row) * 256 + cs * 8, &Bs[idx * 8]);
  }
  __syncthreads();

  s16x8 afr[2][8];   // AGPR-resident (unified file); no class constraints
#pragma unroll
  for (int mi = 0; mi < 2; ++mi) {
    int row = wy + mi * 16 + l16;
#pragma unroll
    for (int ki = 0; ki < 8; ++ki) {
      int cl = (ki * 4 + quad) ^ (row & 7);
      afr[mi][ki] = *(const s16x8*)&Bs[row * 256 + cl * 8];
    }
  }
  __syncthreads();   // hoist reads retired before Bs is overwritten

  f32x4 outacc[2][2];
#pragma unroll
  for (int a = 0; a < 2; ++a)
#pragma unroll
    for (int b = 0; b < 2; ++b) outacc[a][b] = (f32x4){0.f, 0.f, 0.f, 0.f};

  for (int tl = 0; tl < 16; ++tl) {           // tl == d
    const int brow0 = tl * O + ocbase;
#pragma unroll
    for (int p = 0; p < 8; ++p) {
      int idx = p * 256 + t; int row = idx >> 5; int cs = (idx & 31) ^ (row & 7);
      glds16(A.Bt + (size_t)(brow0 + row) * 256 + cs * 8, &Bs[idx * 8]);
    }
    __syncthreads();   // B tile staged

    f32x4 acc[2][2];
#pragma unroll
    for (int a = 0; a < 2; ++a)
#pragma unroll
      for (int b = 0; b < 2; ++b) acc[a][b] = (f32x4){0.f, 0.f, 0.f, 0.f};

#pragma unroll
    for (int ki = 0; ki < 8; ++ki) {
      s16x8 bfr[2];
#pragma unroll
      for (int ni = 0; ni < 2; ++ni) {
        int row = wx + ni * 16 + l16;
        int cl = (ki * 4 + quad) ^ (row & 7);
        bfr[ni] = *(const s16x8*)&Bs[row * 256 + cl * 8];
      }
#pragma unroll
      for (int mi = 0; mi < 2; ++mi)
#pragma unroll
        for (int ni = 0; ni < 2; ++ni)
          acc[mi][ni] = __builtin_amdgcn_mfma_f32_16x16x32_bf16(afr[mi][ki], bfr[ni], acc[mi][ni], 0, 0, 0);
    }

    // fold d: outacc += ew[n,d] * acc
#pragma unroll
    for (int mi = 0; mi < 2; ++mi) {
      int nl = (wy + mi * 16 + quad * 4) >> 3;
      float s = ewS[nl][tl];
#pragma unroll
      for (int ni = 0; ni < 2; ++ni)
#pragma unroll
        for (int r = 0; r < 4; ++r)
          outacc[mi][ni][r] += s * acc[mi][ni][r];
    }
    __syncthreads();   // Bs reads retired before next tile's stage
  }

  // epilogue (gate): bias + sigmoid + ZSt/AgU/Rb writes
#pragma unroll
  for (int mi = 0; mi < 2; ++mi)
#pragma unroll
    for (int ni = 0; ni < 2; ++ni)
#pragma unroll
      for (int r = 0; r < 4; ++r) {
        int row = row0 + wy + mi * 16 + quad * 4 + r;
        int n = row >> 3, b = row & 7;
        int o = ocbase + wx + ni * 16 + l16;
        float pre = outacc[mi][ni][r] + A.Bias[(size_t)mode * 1000 * O + n * O + o];
        float sg = 1.f / (1.f + __expf(-pre));
        if (o < 64) {
          float st = A.state[mode][(b * 1000 + n) * 64 + o];
          float zs = sg * st;
          A.ZSt[(size_t)mode * 524288 + (size_t)(b * 64 + o) * 1024 + n] = (u16)f2bf(zs);
          A.AgU[(size_t)mode * 2048000 + (size_t)row * 256 + 16 + o] = (u16)f2bf(zs);
        } else {
          A.Rb[(size_t)mode * 512000 + row * 64 + (o - 64)] = sg;
        }
      }
}

// ---------------------------------------------------------------------------
// meta3u (update, split-d): grid (2,125,3); dh=blockIdx.x covers d in
// [8dh, 8dh+8) -> 8-tile chain. Writes raw f32 partials to Pacc
// ([2][3][8000][64] overlaid on the dead Ag region). No bias/activation.
// ---------------------------------------------------------------------------
__global__ __launch_bounds__(256, 4) void meta3u(Meta3Args A, float* Pacc) {
  const int mode = blockIdx.z;
  const int row0 = blockIdx.y * 64;
  const int n0 = row0 >> 3;
  const int dh = blockIdx.x;          // d-half: 0 or 1

  __shared__ u16 Bs[64 * 256];
  __shared__ float ewS[8][17];

  const int t = threadIdx.x;
  if (t < 128) {
    int nl = t >> 4, d = t & 15;
    ewS[nl][d] = A.emb[mode][(n0 + nl) * 16 + d] * A.me[mode * 16 + d];
  }

  const int lane = t & 63, wid = t >> 6;
  const int l16 = lane & 15, quad = lane >> 4;
  const int wy = (wid >> 1) * 32, wx = (wid & 1) * 32;
  const u16* Agm = A.Ag + (size_t)mode * 2048000;

#pragma unroll
  for (int p = 0; p < 8; ++p) {
    int idx = p * 256 + t; int row = idx >> 5; int cs = (idx & 31) ^ (row & 7);
    glds16(Agm + (size_t)(row0 + row) * 256 + cs * 8, &Bs[idx * 8]);
  }
  __syncthreads();

  s16x8 afr[2][8];
#pragma unroll
  for (int mi = 0; mi < 2; ++mi) {
    int row = wy + mi * 16 + l16;
#pragma unroll
    for (int ki = 0; ki < 8; ++ki) {
      int cl = (ki * 4 + quad) ^ (row & 7);
      afr[mi][ki] = *(const s16x8*)&Bs[row * 256 + cl * 8];
    }
  }
  __syncthreads();

  f32x4 outacc[2][2];
#pragma unroll
  for (int a = 0; a < 2; ++a)
#pragma unroll
    for (int b = 0; b < 2; ++b) outacc[a][b] = (f32x4){0.f, 0.f, 0.f, 0.f};

  for (int tl = dh * 8; tl < dh * 8 + 8; ++tl) {
    const int brow0 = tl * 64;
#pragma unroll
    for (int p = 0; p < 8; ++p) {
      int idx = p * 256 + t; int row = idx >> 5; int cs = (idx & 31) ^ (row & 7);
      glds16(A.Bt + (size_t)(brow0 + row) * 256 + cs * 8, &Bs[idx * 8]);
    }
    __syncthreads();

    f32x4 acc[2][2];
#pragma unroll
    for (int a = 0; a < 2; ++a)
#pragma unroll
      for (int b = 0; b < 2; ++b) acc[a][b] = (f32x4){0.f, 0.f, 0.f, 0.f};

#pragma unroll
    for (int ki = 0; ki < 8; ++ki) {
      s16x8 bfr[2];
#pragma unroll
      for (int ni = 0; ni < 2; ++ni) {
        int row = wx + ni * 16 + l16;
        int cl = (ki * 4 + quad) ^ (row & 7);
        bfr[ni] = *(const s16x8*)&Bs[row * 256 + cl * 8];
      }
#pragma unroll
      for (int mi = 0; mi < 2; ++mi)
#pragma unroll
        for (int ni = 0; ni < 2; ++ni)
          acc[mi][ni] = __builtin_amdgcn_mfma_f32_16x16x32_bf16(afr[mi][ki], bfr[ni], acc[mi][ni], 0, 0, 0);
    }

#pragma unroll
    for (int mi = 0; mi < 2; ++mi) {
      int nl = (wy + mi * 16 + quad * 4) >> 3;
      float s = ewS[nl][tl];
#pragma unroll
      for (int ni = 0; ni < 2; ++ni)
#pragma unroll
        for (int r = 0; r < 4; ++r)
          outacc[mi][ni][r] += s * acc[mi][ni][r];
    }
    __syncthreads();
  }

  // write raw partials: Pacc[((dh*3+mode)*8000 + row)*64 + o]
#pragma unroll
  for (int mi = 0; mi < 2; ++mi)
#pragma unroll
    for (int ni = 0; ni < 2; ++ni)
#pragma unroll
      for (int r = 0; r < 4; ++r) {
        int row = row0 + wy + mi * 16 + quad * 4 + r;
        int o = wx + ni * 16 + l16;
        Pacc[((size_t)(dh * 3 + mode) * 8000 + row) * 64 + o] = outacc[mi][ni][r];
      }
}

// ---------------------------------------------------------------------------
// epi_u: out = r*state + (1-r)*tanh(p0+p1+BiU). 3*8000*64 = 1.536M threads.
// ---------------------------------------------------------------------------
__global__ void epi_u(const float* __restrict__ Pacc, const float* __restrict__ BiU,
                      const float* __restrict__ Rb,
                      const float* __restrict__ st0, const float* __restrict__ st1,
                      const float* __restrict__ st2, float* __restrict__ out) {
  int idx = blockIdx.x * blockDim.x + threadIdx.x;
  if (idx >= 1536000) return;
  int mode = idx / 512000, rem = idx % 512000;
  int row = rem >> 6, o = rem & 63;
  int n = row >> 3, b = row & 7;
  float pre = Pacc[((size_t)mode * 8000 + row) * 64 + o] +
              Pacc[((size_t)(3 + mode) * 8000 + row) * 64 + o] +
              BiU[(size_t)mode * 64000 + n * 64 + o];
  float hc = tanhf(pre);
  float rr = Rb[(size_t)mode * 512000 + row * 64 + o];
  const float* st = (mode == 0) ? st0 : (mode == 1) ? st1 : st2;
  out[(size_t)mode * 512000 + (b * 1000 + n) * 64 + o] =
      rr * st[(b * 1000 + n) * 64 + o] + (1.f - rr) * hc;
}

// ---------------------------------------------------------------------------
extern "C" void kernel_launch(void* const* d_in, const int* in_sizes, int n_in,
                              void* d_out, int out_size, void* d_ws, size_t ws_size,
                              hipStream_t stream) {
  const float* x[3]   = {(const float*)d_in[0], (const float*)d_in[1], (const float*)d_in[2]};
  const float* st[3]  = {(const float*)d_in[3], (const float*)d_in[4], (const float*)d_in[5]};
  const float* S[3]   = {(const float*)d_in[6], (const float*)d_in[7], (const float*)d_in[8]};
  const float* emb[3] = {(const float*)d_in[9], (const float*)d_in[10], (const float*)d_in[11]};
  const float* me = (const float*)d_in[12];
  const float* Wg = (const float*)d_in[13];
  const float* Bg = (const float*)d_in[14];
  const float* Wu = (const float*)d_in[15];
  const float* Bu = (const float*)d_in[16];
  float* out = (float*)d_out;

  float* BiG = (float*)d_ws;            // 3*1000*128
  float* BiU = BiG + 384000;            // 3*1000*64
  float* Rb  = BiU + 192000;            // 3*8000*64
  u16* S16 = (u16*)(Rb + 1536000);      // 3*1024*1024
  u16* Xt  = S16 + 3145728;             // 3*640*1024
  u16* T1t = Xt + 1966080;              // 3*640*1024
  u16* ZSt = T1t + 1966080;             // 3*512*1024
  u16* SZ1t= ZSt + 1572864;             // 3*512*1024
  u16* Ag  = SZ1t + 1572864;            // 3*8000*256
  u16* AgU = Ag + 6144000;              // 3*8000*256
  u16* BtG = AgU + 6144000;             // 2048*256
  u16* BtU = BtG + 524288;              // 1024*256
  float* PaccU = (float*)Ag;            // overlay: [2][3][8000][64] f32,
                                        // 12.29MB == Ag size; Ag dead after
                                        // gate meta reads it.

  {
    PrepAuxArgs P;
    for (int m = 0; m < 3; ++m) { P.x[m] = x[m]; P.st[m] = st[m]; P.S[m] = S[m]; }
    P.S16 = S16; P.Xt = Xt; P.Ag = Ag; P.AgU = AgU; P.T1t = T1t; P.ZSt = ZSt; P.SZ1t = SZ1t;
    P.e0 = emb[0]; P.e1 = emb[1]; P.e2 = emb[2]; P.me = me;
    P.Bg = Bg; P.Bu = Bu; P.Wg = Wg; P.Wu = Wu;
    P.BiG = BiG; P.BiU = BiU; P.BtG = BtG; P.BtU = BtU;
    prep_aux<<<13431, 256, 0, stream>>>(P);
  }

  // cheb1: T1t = Xt @ S^T -> T1t + Ag[80..159] (+AgU x-part)
  {
    ChebArgs2 a;
    for (int m = 0; m < 3; ++m) {
      a.S16[m] = S16 + (size_t)m * 1048576; a.A[m] = Xt + (size_t)m * 655360;
      a.Res[m] = nullptr; a.Yt[m] = T1t + (size_t)m * 655360;
      a.AgA[m] = Ag + (size_t)m * 2048000; a.AgX[m] = AgU + (size_t)m * 2048000;
    }
    cheb_v6<<<dim3(16, 20, 3), 256, 0, stream>>>(a, 80, 80, 1.f, 0.f, 2 | 4);
  }
  // cheb2: T2t = 2*T1t @ S^T - Xt -> Ag[160..239] (+AgU x-part)
  {
    ChebArgs2 a;
    for (int m = 0; m < 3; ++m) {
      a.S16[m] = S16 + (size_t)m * 1048576; a.A[m] = T1t + (size_t)m * 655360;
      a.Res[m] = Xt + (size_t)m * 655360; a.Yt[m] = nullptr;
      a.AgA[m] = Ag + (size_t)m * 2048000; a.AgX[m] = AgU + (size_t)m * 2048000;
    }
    cheb_v6<<<dim3(16, 20, 3), 256, 0, stream>>>(a, 80, 160, 2.f, -1.f, 1 | 4);
  }
  // gate meta: reads Ag; writes ZSt + AgU[16..79] + Rb  (oc split: grid.x=2)
  {
    Meta3Args a;
    a.Ag = Ag; a.Bt = BtG; a.me = me; a.Bias = BiG;
    a.ZSt = ZSt; a.AgU = AgU; a.Rb = Rb; a.out = out;
    for (int m = 0; m < 3; ++m) { a.emb[m] = emb[m]; a.state[m] = st[m]; }
    meta3<<<dim3(2, 125, 3), 256, 0, stream>>>(a, 1, 128);
  }
  // cheb3: SZ1t = ZSt @ S^T -> SZ1t + AgU[96..159]
  {
    ChebArgs2 a;
    for (int m = 0; m < 3; ++m) {
      a.S16[m] = S16 + (size_t)m * 1048576; a.A[m] = ZSt + (size_t)m * 524288;
      a.Res[m] = nullptr; a.Yt[m] = SZ1t + (size_t)m * 524288;
      a.AgA[m] = AgU + (size_t)m * 2048000; a.AgX[m] = nullptr;
    }
    cheb_v6<<<dim3(16, 16, 3), 256, 0, stream>>>(a, 64, 96, 1.f, 0.f, 2);
  }
  // cheb4: SZ2t = 2*SZ1t @ S^T - ZSt -> AgU[176..239]
  {
    ChebArgs2 a;
    for (int m = 0; m < 3; ++m) {
      a.S16[m] = S16 + (size_t)m * 1048576; a.A[m] = SZ1t + (size_t)m * 524288;
      a.Res[m] = ZSt + (size_t)m * 524288; a.Yt[m] = nullptr;
      a.AgA[m] = AgU + (size_t)m * 2048000; a.AgX[m] = nullptr;
    }
    cheb_v6<<<dim3(16, 16, 3), 256, 0, stream>>>(a, 64, 176, 2.f, -1.f, 1);
  }
  // update meta (split-d): reads AgU; writes PaccU partials (Ag overlay)
  {
    Meta3Args a;
    a.Ag = AgU; a.Bt = BtU; a.me = me; a.Bias = BiU;
    a.ZSt = ZSt; a.AgU = AgU; a.Rb = Rb; a.out = out;
    for (int m = 0; m < 3; ++m) { a.emb[m] = emb[m]; a.state[m] = st[m]; }
    meta3u<<<dim3(2, 125, 3), 256, 0, stream>>>(a, PaccU);
  }
  // update epilogue: out = r*state + (1-r)*tanh(p0+p1+BiU)
  epi_u<<<6000, 256, 0, stream>>>(PaccU, BiU, Rb, st[0], st[1], st[2], out);
}